// Round 1
// 170.095 us; speedup vs baseline: 1.0126x; 1.0126x over previous
//
#include <hip/hip_runtime.h>

// ---------------- problem constants ----------------
constexpr int nB = 2;       // batch
constexpr int nS = 512;     // seq len
constexpr int nH = 768;     // hidden
constexpr int nC = 108;     // channels
constexpr int nD = 64;      // head size
constexpr int nBC = nB * nC;          // 216
constexpr long long nSS = (long long)nS * nS;  // 262144

// ---------------- workspace layout (floats, in d_ws) ----------------
constexpr size_t QW_OFF    = 0;                         // 2*512*64 = 65536
constexpr size_t KW_OFF    = QW_OFF + (size_t)nB*nS*nD; // 65536
constexpr size_t EV_OFF    = KW_OFF + (size_t)nB*nS*nD; // 131072
constexpr size_t MAX_OFF   = EV_OFF + (size_t)nC*nD;    // 137984
constexpr size_t SCALE_OFF = MAX_OFF + nBC;             // 138200
constexpr size_t COMP_OFF  = SCALE_OFF + nBC;           // 138416
constexpr size_t SIG_OFF   = COMP_OFF + (size_t)nB*2*nS*nS;  // 1186992
// qw/kw column sums (2b * {q,k} * 64d = 256 floats). Aliases the sig region:
// written by k1 (atomics, zeroed by memset), read by kC preamble, overwritten by k5.
constexpr size_t SQK_OFF   = SIG_OFF;

typedef __attribute__((ext_vector_type(8))) short short8;
typedef __attribute__((ext_vector_type(4))) float f32x4;
union UFrag { uint4 u; short8 s; };

__device__ inline void atomicMaxF(float* addr, float v) {
    if (v >= 0.f) atomicMax((int*)addr, __float_as_int(v));
    else          atomicMin((unsigned int*)addr, __float_as_uint(v));
}

// round-to-nearest-even f32 -> bf16, packed pair
__device__ inline unsigned pack2bf(float a, float b) {
    unsigned ua = __float_as_uint(a), ub = __float_as_uint(b);
    ua = (ua + 0x7FFFu + ((ua >> 16) & 1u)) >> 16;
    ub = (ub + 0x7FFFu + ((ub >> 16) & 1u)) >> 16;
    return ua | (ub << 16);
}

// ---------------- K1: seq = in@Wd+bd, RoPE -> qw,kw ; ev = evin@We+be ----------------
// v2: 4 rows per block, k split across thread halves; wd L2 traffic 445MB -> 100MB.
// Also accumulates per-(b,d) column sums of qw/kw into SQK (for factored spatial mean).
__global__ __launch_bounds__(256) void k1_proj(
    const float* __restrict__ in, const float* __restrict__ evin,
    const float* __restrict__ wd, const float* __restrict__ bd,
    const float* __restrict__ we, const float* __restrict__ be,
    float* __restrict__ ws)
{
    __shared__ float rowT[nH][4];       // transposed rows: rowT[k][r], 12 KB
    __shared__ float accS[2][4][128];   // per-half partial sums
    __shared__ float ropeS[2][4][64];   // rope outputs for column-sum reduce
    const int blk = blockIdx.x, tid = threadIdx.x;
    if (blk == 0 && tid < nBC) ws[MAX_OFF + tid] = -INFINITY;
    if (blk < 256) {
        const int b = blk >> 7;
        const int m0 = (blk & 127) << 2;
        const float* src = in + ((size_t)(b * nS + m0)) * nH;
        for (int q = tid; q < 4 * nH; q += 256) {
            const int r = q / nH, k = q - r * nH;
            rowT[k][r] = src[q];
        }
        __syncthreads();
        const int h = tid >> 7, c = tid & 127;
        float a0 = h ? 0.f : bd[c], a1 = 0.f, a2 = 0.f, a3 = 0.f;
        const float* wp = wd + (size_t)(h * 384) * 128 + c;
        for (int k = h * 384; k < h * 384 + 384; ++k, wp += 128) {
            const float w = *wp;
            const float4 rv = *(const float4*)&rowT[k][0];
            a0 += rv.x * w; a1 += rv.y * w; a2 += rv.z * w; a3 += rv.w * w;
        }
        accS[h][0][c] = a0; accS[h][1][c] = a1; accS[h][2][c] = a2; accS[h][3][c] = a3;
        __syncthreads();
        const int r = tid >> 6, j = tid & 63;
        const int m = m0 + r;
        const int p = j >> 1;
        const float div = expf(-0.28782313662425572f * (float)p);
        const float ang = (float)m * div;
        const float co = cosf(ang), si = sinf(ang);
#pragma unroll
        for (int half = 0; half < 2; ++half) {
            const int i0 = half * 64 + (j & ~1);
            const int i1 = half * 64 + (j | 1);
            const float x0 = accS[0][r][i0] + accS[1][r][i0];
            const float x1 = accS[0][r][i1] + accS[1][r][i1];
            const float v = (j & 1) ? (x1 * co + x0 * si) : (x0 * co - x1 * si);
            ws[(half ? KW_OFF : QW_OFF) + ((size_t)(b * nS + m)) * nD + j] = v;
            ropeS[half][r][j] = v;
        }
        __syncthreads();
        if (tid < 128) {
            const int half = tid >> 6, jj = tid & 63;
            const float t = ropeS[half][0][jj] + ropeS[half][1][jj]
                          + ropeS[half][2][jj] + ropeS[half][3][jj];
            atomicAdd(&ws[SQK_OFF + b * 128 + half * 64 + jj], t);
        }
    } else {
        const int ci = blk - 256;
        float* evrow = &rowT[0][0];   // flat 768 floats
        for (int k = tid; k < nH; k += 256) evrow[k] = evin[(size_t)ci * nH + k];
        __syncthreads();
        const int c = tid & 63, h = tid >> 6;   // 4 k-slices of 192
        float acc = 0.f;
        for (int k = h * 192; k < h * 192 + 192; ++k) acc += evrow[k] * we[k * nD + c];
        accS[0][h][c] = acc;
        __syncthreads();
        if (tid < nD) {
            const float s = be[tid] + accS[0][0][tid] + accS[0][1][tid]
                          + accS[0][2][tid] + accS[0][3][tid];
            ws[EV_OFF + (size_t)ci * nD + tid] = s;
        }
    }
}

// ======== shared machinery for the ev-as-A einsum (kS / kC) ========
__device__ inline void stage_ev(const float* __restrict__ ws, uint4* evS, int tid) {
    for (int idx = tid; idx < 112 * 8; idx += 256) {
        const int row = idx >> 3, g = idx & 7;
        uint4 u = make_uint4(0, 0, 0, 0);
        if (row < nC) {
            const float* ep = ws + EV_OFF + row * nD + g * 8;
            float4 a = *(const float4*)ep;
            float4 b = *(const float4*)(ep + 4);
            u.x = pack2bf(a.x, a.y); u.y = pack2bf(a.z, a.w);
            u.z = pack2bf(b.x, b.y); u.w = pack2bf(b.z, b.w);
        }
        evS[row * 8 + (g ^ (row & 7))] = u;
    }
}

__device__ inline void stage_qk(const float* __restrict__ ws, float (*qkS)[68],
                                int b, int m0, int n0, int tid) {
    for (int idx = tid; idx < 64 * 16; idx += 256) {
        const int row = idx >> 4, d4 = (idx & 15) * 4;
        const float* src = (row < 32)
            ? (ws + QW_OFF + ((size_t)(b * nS + m0 + row)) * nD + d4)
            : (ws + KW_OFF + ((size_t)(b * nS + n0 + (row - 32))) * nD + d4);
        const float4 v = *(const float4*)src;
        qkS[row][d4 + 0] = v.x; qkS[row][d4 + 1] = v.y;
        qkS[row][d4 + 2] = v.z; qkS[row][d4 + 3] = v.w;
    }
}

__device__ inline void build_U(const float (*qkS)[68], uint4* U, int si, int sj, int tid) {
    const float* qr = qkS[si * 16 + (tid >> 4)];
    const float* kr = qkS[32 + sj * 16 + (tid & 15)];
#pragma unroll
    for (int g = 0; g < 8; ++g) {
        uint4 u;
        u.x = pack2bf(qr[g*8+0]*kr[g*8+0], qr[g*8+1]*kr[g*8+1]);
        u.y = pack2bf(qr[g*8+2]*kr[g*8+2], qr[g*8+3]*kr[g*8+3]);
        u.z = pack2bf(qr[g*8+4]*kr[g*8+4], qr[g*8+5]*kr[g*8+5]);
        u.w = pack2bf(qr[g*8+6]*kr[g*8+6], qr[g*8+7]*kr[g*8+7]);
        U[tid * 8 + (g ^ (tid & 7))] = u;
    }
}

// ---------------- kS: einsum pass 1 -> per-(b,c) max only (sum is factorized) ----------------
__global__ __launch_bounds__(256) void kS_stats(float* __restrict__ ws)
{
    __shared__ uint4 evS[112 * 8];
    __shared__ uint4 U[256 * 8];
    __shared__ float qkS[64][68];
    __shared__ float mS[4][112];

    const int tid = threadIdx.x;
    const int b = blockIdx.y;
    const int m0 = (blockIdx.x >> 4) * 32, n0 = (blockIdx.x & 15) * 32;
    const int lane = tid & 63, w = tid >> 6;
    const int fr = lane & 15, fg = lane >> 4;

    stage_ev(ws, evS, tid);
    stage_qk(ws, qkS, b, m0, n0, tid);

    float pmax[28];
#pragma unroll
    for (int i = 0; i < 28; ++i) pmax[i] = -INFINITY;

    for (int st = 0; st < 4; ++st) {
        __syncthreads();
        build_U(qkS, U, st >> 1, st & 1, tid);
        __syncthreads();

        short8 uf[4][2];
#pragma unroll
        for (int nf = 0; nf < 4; ++nf)
#pragma unroll
            for (int ks = 0; ks < 2; ++ks) {
                const int row = w * 64 + nf * 16 + fr;
                UFrag u; u.u = U[row * 8 + ((ks * 4 + fg) ^ (row & 7))];
                uf[nf][ks] = u.s;
            }
#pragma unroll
        for (int cf = 0; cf < 7; ++cf) {
            short8 ef[2];
#pragma unroll
            for (int ks = 0; ks < 2; ++ks) {
                const int row = cf * 16 + fr;
                UFrag u; u.u = evS[row * 8 + ((ks * 4 + fg) ^ (row & 7))];
                ef[ks] = u.s;
            }
            f32x4 acc[4] = {};
#pragma unroll
            for (int ks = 0; ks < 2; ++ks)
#pragma unroll
                for (int nf = 0; nf < 4; ++nf)
                    acc[nf] = __builtin_amdgcn_mfma_f32_16x16x32_bf16(ef[ks], uf[nf][ks], acc[nf], 0, 0, 0);
#pragma unroll
            for (int nf = 0; nf < 4; ++nf)
#pragma unroll
                for (int r = 0; r < 4; ++r)
                    pmax[cf * 4 + r] = fmaxf(pmax[cf * 4 + r], acc[nf][r]);
        }
    }

    // reduce over the 16 mn-columns (low 4 lane bits)
#pragma unroll
    for (int i = 0; i < 28; ++i) {
#pragma unroll
        for (int off = 1; off < 16; off <<= 1)
            pmax[i] = fmaxf(pmax[i], __shfl_xor(pmax[i], off, 64));
    }
    if (fr == 0) {
#pragma unroll
        for (int cf = 0; cf < 7; ++cf)
#pragma unroll
            for (int r = 0; r < 4; ++r)
                mS[w][cf * 16 + fg * 4 + r] = pmax[cf * 4 + r];
    }
    __syncthreads();
    if (tid < nC) {
        const float mx = fmaxf(fmaxf(mS[0][tid], mS[1][tid]), fmaxf(mS[2][tid], mS[3][tid]));
        atomicMaxF(&ws[MAX_OFF + b * nC + tid], mx);
    }
}

// ---------------- kC: einsum pass 2 -> comp[b,{max,mean over c}] (inline MLP) ----------------
// v2: avg from factored sum (SQK); strictly-lower tiles beyond conv halo skipped.
__global__ __launch_bounds__(256) void kC_comp(
    float* __restrict__ ws, const float* __restrict__ w1, const float* __restrict__ b1,
    const float* __restrict__ w2, const float* __restrict__ b2)
{
    __shared__ uint4 evS[112 * 8];
    __shared__ uint4 U[256 * 8];
    __shared__ float qkS[64][68];
    __shared__ float hS[12], scS[112];
    __shared__ float prodS[64], avgS[112];

    const int tid = threadIdx.x;
    const int b = blockIdx.y;
    const int m0 = (blockIdx.x >> 4) * 32, n0 = (blockIdx.x & 15) * 32;

    // comp only needed where some sig output (n >= (m>>7)<<7) can read it (3-halo)
    {
        const int mlo = m0 > 3 ? m0 - 3 : 0;
        const int ncut = ((mlo >> 7) << 7) - 3;
        if (n0 + 31 < ncut) return;        // blockIdx.x==0 never skipped
    }

    const int lane = tid & 63, w = tid >> 6;
    const int fr = lane & 15, fg = lane >> 4;

    if (tid < 64) {
        const float sq = ws[SQK_OFF + b * 128 + tid];
        const float sk = ws[SQK_OFF + b * 128 + 64 + tid];
        prodS[tid] = sq * sk;
    }
    stage_ev(ws, evS, tid);
    stage_qk(ws, qkS, b, m0, n0, tid);
    __syncthreads();
    if (tid < nC) {   // avg[c] = (1/S^2) * sum_d ev[c,d]*Sq[d]*Sk[d]
        const float* ep = ws + EV_OFF + (size_t)tid * nD;
        float a = 0.f;
#pragma unroll 8
        for (int d = 0; d < nD; ++d) a += ep[d] * prodS[d];
        avgS[tid] = a * (1.f / (float)nSS);
    }
    __syncthreads();
    if (tid < 12) {
        const int src = tid / 6, j = tid % 6;
        float acc = b1[j];
        if (src == 0) {
            for (int cc = 0; cc < nC; ++cc) acc += avgS[cc] * w1[cc * 6 + j];
        } else {
            const float* v = ws + MAX_OFF + b * nC;
            for (int cc = 0; cc < nC; ++cc) acc += v[cc] * w1[cc * 6 + j];
        }
        hS[tid] = fmaxf(acc, 0.f);
    }
    __syncthreads();
    if (tid < 112) {
        float s = 0.f;
        if (tid < nC) {
            float acc = 2.f * b2[tid];
#pragma unroll
            for (int j = 0; j < 6; ++j) acc += (hS[j] + hS[6 + j]) * w2[j * nC + tid];
            s = 1.f / (1.f + expf(-acc));
            if (blockIdx.x == 0) ws[SCALE_OFF + b * nC + tid] = s;  // publish for k6
        }
        scS[tid] = s;
    }

    for (int st = 0; st < 4; ++st) {
        const int si = st >> 1, sj = st & 1;
        __syncthreads();
        build_U(qkS, U, si, sj, tid);
        __syncthreads();

        short8 uf[4][2];
#pragma unroll
        for (int nf = 0; nf < 4; ++nf)
#pragma unroll
            for (int ks = 0; ks < 2; ++ks) {
                const int row = w * 64 + nf * 16 + fr;
                UFrag u; u.u = U[row * 8 + ((ks * 4 + fg) ^ (row & 7))];
                uf[nf][ks] = u.s;
            }
        float mx[4], sm[4];
#pragma unroll
        for (int nf = 0; nf < 4; ++nf) { mx[nf] = -INFINITY; sm[nf] = 0.f; }
#pragma unroll
        for (int cf = 0; cf < 7; ++cf) {
            short8 ef[2];
#pragma unroll
            for (int ks = 0; ks < 2; ++ks) {
                const int row = cf * 16 + fr;
                UFrag u; u.u = evS[row * 8 + ((ks * 4 + fg) ^ (row & 7))];
                ef[ks] = u.s;
            }
            f32x4 acc[4] = {};
#pragma unroll
            for (int ks = 0; ks < 2; ++ks)
#pragma unroll
                for (int nf = 0; nf < 4; ++nf)
                    acc[nf] = __builtin_amdgcn_mfma_f32_16x16x32_bf16(ef[ks], uf[nf][ks], acc[nf], 0, 0, 0);
            const bool valid = (cf < 6) || (fg < 3);   // c < 108
#pragma unroll
            for (int nf = 0; nf < 4; ++nf)
#pragma unroll
                for (int r = 0; r < 4; ++r) {
                    const float v = scS[cf * 16 + fg * 4 + r] * acc[nf][r];
                    sm[nf] += v;
                    if (valid) mx[nf] = fmaxf(mx[nf], v);
                }
        }
#pragma unroll
        for (int nf = 0; nf < 4; ++nf) {
            mx[nf] = fmaxf(mx[nf], __shfl_xor(mx[nf], 16, 64));
            mx[nf] = fmaxf(mx[nf], __shfl_xor(mx[nf], 32, 64));
            sm[nf] += __shfl_xor(sm[nf], 16, 64);
            sm[nf] += __shfl_xor(sm[nf], 32, 64);
        }
        if (fg == 0) {
#pragma unroll
            for (int nf = 0; nf < 4; ++nf) {
                const int m = m0 + si * 16 + 4 * w + nf;
                const int n = n0 + sj * 16 + fr;
                ws[COMP_OFF + (((size_t)(b * 2 + 0)) * nS + m) * nS + n] = mx[nf];
                ws[COMP_OFF + (((size_t)(b * 2 + 1)) * nS + m) * nS + n] = sm[nf] * (1.f / (float)nC);
            }
        }
    }
}

// ---------------- K5: 7x7 conv on comp + sigmoid -> sig[b,m,n] (only n >= row's 128-block) ----------------
__global__ __launch_bounds__(512) void k5_conv(float* __restrict__ ws, const float* __restrict__ cw)
{
    __shared__ float S[14][520];
    __shared__ float wS[98];
    const int n = threadIdx.x;
    const int m = blockIdx.x & 511;
    const int b = blockIdx.x >> 9;
    const int n0q = (m >> 7) << 7;       // sig only consumed for n >= n0q
    if (n < 98) wS[n] = cw[n];
    for (int idx = n; idx < 14 * 518; idx += 512) {
        const int col = idx % 518;
        const int r = idx / 518;
        const int ch = r / 7, ky = r % 7;
        const int y = m + ky - 3;
        const int x = col - 3;
        float v = 0.f;
        if (y >= 0 && y < nS && x >= n0q - 3 && x < nS)
            v = ws[COMP_OFF + (((size_t)(b * 2 + ch)) * nS + y) * nS + x];
        S[r][col] = v;
    }
    __syncthreads();
    if (n >= n0q) {
        float acc = 0.f;
#pragma unroll
        for (int r = 0; r < 14; ++r)
#pragma unroll
            for (int kx = 0; kx < 7; ++kx)
                acc += S[r][n + kx] * wS[r * 7 + kx];
        acc *= 0.9999950000374997f;          // 1/sqrt(1+1e-5)
        ws[SIG_OFF + ((size_t)b * nS + m) * nS + n] = 1.f / (1.f + expf(-acc));
    }
}

// ---------------- staging + mfma helpers for k6 ----------------
__device__ inline void stage_tiles(const float* qwp, const float* kwp, const float* evp,
                                   uint4* ldsA, uint4* ldsB, int tid)
{
#pragma unroll
    for (int i = 0; i < 4; ++i) {
        const int q = tid + i * 256;
        const int row = q >> 3, g = q & 7;
        const int sw = row * 8 + (g ^ (row & 7));
        float4 x0 = *(const float4*)(qwp + row * nD + g * 8);
        float4 x1 = *(const float4*)(qwp + row * nD + g * 8 + 4);
        float4 e0 = *(const float4*)(evp + g * 8);
        float4 e1 = *(const float4*)(evp + g * 8 + 4);
        uint4 w;
        w.x = pack2bf(x0.x * e0.x, x0.y * e0.y);
        w.y = pack2bf(x0.z * e0.z, x0.w * e0.w);
        w.z = pack2bf(x1.x * e1.x, x1.y * e1.y);
        w.w = pack2bf(x1.z * e1.z, x1.w * e1.w);
        ldsA[sw] = w;
        float4 y0 = *(const float4*)(kwp + row * nD + g * 8);
        float4 y1 = *(const float4*)(kwp + row * nD + g * 8 + 4);
        uint4 v;
        v.x = pack2bf(y0.x, y0.y);
        v.y = pack2bf(y0.z, y0.w);
        v.z = pack2bf(y1.x, y1.y);
        v.w = pack2bf(y1.z, y1.w);
        ldsB[sw] = v;
    }
}

__device__ inline void mfma_tile(const uint4* ldsA, const uint4* ldsB,
                                 int wr, int wc, int fr, int fg, f32x4 acc[4][4])
{
#pragma unroll
    for (int ks = 0; ks < 2; ++ks) {
        short8 kf[4], qf[4];
#pragma unroll
        for (int i = 0; i < 4; ++i) {
            const int row = wc * 64 + i * 16 + fr;
            const int g = ks * 4 + fg;
            UFrag u; u.u = ldsB[row * 8 + (g ^ (row & 7))];
            kf[i] = u.s;
        }
#pragma unroll
        for (int j = 0; j < 4; ++j) {
            const int row = wr * 64 + j * 16 + fr;
            const int g = ks * 4 + fg;
            UFrag u; u.u = ldsA[row * 8 + (g ^ (row & 7))];
            qf[j] = u.s;
        }
#pragma unroll
        for (int i = 0; i < 4; ++i)
#pragma unroll
            for (int j = 0; j < 4; ++j)
                acc[i][j] = __builtin_amdgcn_mfma_f32_16x16x32_bf16(kf[i], qf[j], acc[i][j], 0, 0, 0);
    }
}

// ---------------- K6: recompute einsum, apply (1+scale*sig), mask, tril, /8 ----------------
// Strictly-lower 128-tiles: (x - 1e12) rounds to exactly -1e12 in fp32 (ULP=65536),
// so the tile is the bit-exact constant -1e12/8 (or -inf under mask) -> pure fill.
__global__ __launch_bounds__(256) void k6_final(
    float* __restrict__ ws, float* __restrict__ out, const int* __restrict__ mask)
{
    __shared__ uint4 ldsA[128 * 8];
    __shared__ uint4 ldsB[128 * 8];

    const int tid = threadIdx.x;
    const int mt = blockIdx.x >> 2, nt = blockIdx.x & 3;
    const int c  = blockIdx.y;
    const int b  = blockIdx.z;
    const int m0 = mt * 128, n0 = nt * 128;
    float* outb = out + (size_t)(b * nC + c) * nSS;

    if (mt > nt) {   // strictly lower: constant fill, coalesced 512B/row per wave
        const float CF = -1e12f * 0.125f;
        const int rr0 = tid >> 5;
        const int nn = n0 + (tid & 31) * 4;
        const int4 mc = *(const int4*)(mask + b * nS + nn);
#pragma unroll
        for (int p = 0; p < 16; ++p) {
            const int m = m0 + p * 8 + rr0;
            const int mr = mask[b * nS + m];
            float4 v;
            v.x = (mr && mc.x) ? CF : -INFINITY;
            v.y = (mr && mc.y) ? CF : -INFINITY;
            v.z = (mr && mc.z) ? CF : -INFINITY;
            v.w = (mr && mc.w) ? CF : -INFINITY;
            *(float4*)(outb + (size_t)m * nS + nn) = v;
        }
        return;
    }

    stage_tiles(ws + QW_OFF + ((size_t)(b * nS + m0)) * nD,
                ws + KW_OFF + ((size_t)(b * nS + n0)) * nD,
                ws + EV_OFF + (size_t)c * nD, ldsA, ldsB, tid);
    __syncthreads();

    const int lane = tid & 63;
    const int wv = tid >> 6;
    const int wr = wv >> 1, wc = wv & 1;
    const int fr = lane & 15, fg = lane >> 4;

    f32x4 acc[4][4] = {};
    mfma_tile(ldsA, ldsB, wr, wc, fr, fg, acc);

    const float scale = ws[SCALE_OFF + b * nC + c];
    const float* sig = ws + SIG_OFF + (size_t)b * nS * nS;

#pragma unroll
    for (int i = 0; i < 4; ++i) {
#pragma unroll
        for (int j = 0; j < 4; ++j) {
            const int m = m0 + wr * 64 + j * 16 + fr;
            const int nb = n0 + wc * 64 + i * 16 + fg * 4;
            const float4 sg = *(const float4*)(sig + (size_t)m * nS + nb);
            const int mrow = mask[b * nS + m];
            const int4 mcol = *(const int4*)(mask + b * nS + nb);
            const f32x4 a = acc[i][j];
            float r[4];
            const float sgv[4] = { sg.x, sg.y, sg.z, sg.w };
            const int mcv[4] = { mcol.x, mcol.y, mcol.z, mcol.w };
#pragma unroll
            for (int rr = 0; rr < 4; ++rr) {
                float v = a[rr] * (1.f + scale * sgv[rr]);
                if (!mrow || !mcv[rr]) v = -INFINITY;
                if (m > nb + rr) v -= 1e12f;
                r[rr] = v * 0.125f;
            }
            *(float4*)(outb + (size_t)m * nS + nb) = make_float4(r[0], r[1], r[2], r[3]);
        }
    }
}

extern "C" void kernel_launch(void* const* d_in, const int* in_sizes, int n_in,
                              void* d_out, int out_size, void* d_ws, size_t ws_size,
                              hipStream_t stream)
{
    const float* inputs = (const float*)d_in[0];
    const float* evin   = (const float*)d_in[1];
    const int*   mask   = (const int*)d_in[2];
    const float* wd     = (const float*)d_in[3];
    const float* bd     = (const float*)d_in[4];
    const float* we     = (const float*)d_in[5];
    const float* be     = (const float*)d_in[6];
    const float* w1     = (const float*)d_in[7];
    const float* b1     = (const float*)d_in[8];
    const float* w2     = (const float*)d_in[9];
    const float* b2     = (const float*)d_in[10];
    const float* cw     = (const float*)d_in[11];
    float* out = (float*)d_out;
    float* ws  = (float*)d_ws;

    hipMemsetAsync((char*)d_ws + SQK_OFF * sizeof(float), 0, 256 * sizeof(float), stream);
    k1_proj<<<256 + nC, 256, 0, stream>>>(inputs, evin, wd, bd, we, be, ws);
    kS_stats<<<dim3(256, nB), 256, 0, stream>>>(ws);
    kC_comp<<<dim3(256, nB), 256, 0, stream>>>(ws, w1, b1, w2, b2);
    k5_conv<<<nB * nS, 512, 0, stream>>>(ws, cw);
    k6_final<<<dim3(16, nC, nB), 256, 0, stream>>>(ws, out, mask);
}

// Round 2
// 161.006 us; speedup vs baseline: 1.0698x; 1.0564x over previous
//
#include <hip/hip_runtime.h>

// ---------------- problem constants ----------------
constexpr int nB = 2;       // batch
constexpr int nS = 512;     // seq len
constexpr int nH = 768;     // hidden
constexpr int nC = 108;     // channels
constexpr int nD = 64;      // head size
constexpr int nBC = nB * nC;          // 216
constexpr long long nSS = (long long)nS * nS;  // 262144

// ---------------- workspace layout (floats, in d_ws) ----------------
constexpr size_t QW_OFF    = 0;                         // 2*512*64 = 65536
constexpr size_t KW_OFF    = QW_OFF + (size_t)nB*nS*nD; // 65536
constexpr size_t EV_OFF    = KW_OFF + (size_t)nB*nS*nD; // 131072
constexpr size_t MAX_OFF   = EV_OFF + (size_t)nC*nD;    // 137984
constexpr size_t SCALE_OFF = MAX_OFF + nBC;             // 138200
constexpr size_t COMP_OFF  = SCALE_OFF + nBC;           // 138416
constexpr size_t SIG_OFF   = COMP_OFF + (size_t)nB*2*nS*nS;  // 1186992
// qw/kw per-block column-sum partials: [b][blk127][ {q:64, k:64} ] = 32768 floats.
// Aliases sig rows b=0,m=0..63 — written by k1, read by kC, overwritten by k5 before k6.
constexpr size_t SQK_OFF   = SIG_OFF;

typedef __attribute__((ext_vector_type(8))) short short8;
typedef __attribute__((ext_vector_type(4))) float f32x4;
union UFrag { uint4 u; short8 s; };

__device__ inline void atomicMaxF(float* addr, float v) {
    if (v >= 0.f) atomicMax((int*)addr, __float_as_int(v));
    else          atomicMin((unsigned int*)addr, __float_as_uint(v));
}

// round-to-nearest-even f32 -> bf16, packed pair
__device__ inline unsigned pack2bf(float a, float b) {
    unsigned ua = __float_as_uint(a), ub = __float_as_uint(b);
    ua = (ua + 0x7FFFu + ((ua >> 16) & 1u)) >> 16;
    ub = (ub + 0x7FFFu + ((ub >> 16) & 1u)) >> 16;
    return ua | (ub << 16);
}

// ---------------- K1: seq = in@Wd+bd, RoPE -> qw,kw ; ev = evin@We+be ----------------
// 4 rows per block, k split across thread halves. Per-block qw/kw column-sum
// partials -> SQK (no atomics, no memset; deterministic).
__global__ __launch_bounds__(256) void k1_proj(
    const float* __restrict__ in, const float* __restrict__ evin,
    const float* __restrict__ wd, const float* __restrict__ bd,
    const float* __restrict__ we, const float* __restrict__ be,
    float* __restrict__ ws)
{
    __shared__ float rowT[nH][4];       // transposed rows: rowT[k][r], 12 KB
    __shared__ float accS[2][4][128];   // per-half partial sums
    __shared__ float ropeS[2][4][64];   // rope outputs for column-sum reduce
    const int blk = blockIdx.x, tid = threadIdx.x;
    if (blk == 0 && tid < nBC) ws[MAX_OFF + tid] = -INFINITY;
    if (blk < 256) {
        const int b = blk >> 7;
        const int m0 = (blk & 127) << 2;
        const float* src = in + ((size_t)(b * nS + m0)) * nH;
        for (int q = tid; q < 4 * nH; q += 256) {
            const int r = q / nH, k = q - r * nH;
            rowT[k][r] = src[q];
        }
        __syncthreads();
        const int h = tid >> 7, c = tid & 127;
        float a0 = h ? 0.f : bd[c], a1 = 0.f, a2 = 0.f, a3 = 0.f;
        const float* wp = wd + (size_t)(h * 384) * 128 + c;
        for (int k = h * 384; k < h * 384 + 384; ++k, wp += 128) {
            const float w = *wp;
            const float4 rv = *(const float4*)&rowT[k][0];
            a0 += rv.x * w; a1 += rv.y * w; a2 += rv.z * w; a3 += rv.w * w;
        }
        accS[h][0][c] = a0; accS[h][1][c] = a1; accS[h][2][c] = a2; accS[h][3][c] = a3;
        __syncthreads();
        const int r = tid >> 6, j = tid & 63;
        const int m = m0 + r;
        const int p = j >> 1;
        const float div = expf(-0.28782313662425572f * (float)p);
        const float ang = (float)m * div;
        const float co = cosf(ang), si = sinf(ang);
#pragma unroll
        for (int half = 0; half < 2; ++half) {
            const int i0 = half * 64 + (j & ~1);
            const int i1 = half * 64 + (j | 1);
            const float x0 = accS[0][r][i0] + accS[1][r][i0];
            const float x1 = accS[0][r][i1] + accS[1][r][i1];
            const float v = (j & 1) ? (x1 * co + x0 * si) : (x0 * co - x1 * si);
            ws[(half ? KW_OFF : QW_OFF) + ((size_t)(b * nS + m)) * nD + j] = v;
            ropeS[half][r][j] = v;
        }
        __syncthreads();
        if (tid < 128) {
            const int half = tid >> 6, jj = tid & 63;
            const float t = ropeS[half][0][jj] + ropeS[half][1][jj]
                          + ropeS[half][2][jj] + ropeS[half][3][jj];
            ws[SQK_OFF + ((size_t)(b * 128 + (blk & 127))) * 128 + half * 64 + jj] = t;
        }
    } else {
        const int ci = blk - 256;
        float* evrow = &rowT[0][0];   // flat 768 floats
        for (int k = tid; k < nH; k += 256) evrow[k] = evin[(size_t)ci * nH + k];
        __syncthreads();
        const int c = tid & 63, h = tid >> 6;   // 4 k-slices of 192
        float acc = 0.f;
        for (int k = h * 192; k < h * 192 + 192; ++k) acc += evrow[k] * we[k * nD + c];
        accS[0][h][c] = acc;
        __syncthreads();
        if (tid < nD) {
            const float s = be[tid] + accS[0][0][tid] + accS[0][1][tid]
                          + accS[0][2][tid] + accS[0][3][tid];
            ws[EV_OFF + (size_t)ci * nD + tid] = s;
        }
    }
}

// ======== shared machinery for the ev-as-A einsum (kS / kC) ========
__device__ inline void stage_ev(const float* __restrict__ ws, uint4* evS, int tid) {
    for (int idx = tid; idx < 112 * 8; idx += 256) {
        const int row = idx >> 3, g = idx & 7;
        uint4 u = make_uint4(0, 0, 0, 0);
        if (row < nC) {
            const float* ep = ws + EV_OFF + row * nD + g * 8;
            float4 a = *(const float4*)ep;
            float4 b = *(const float4*)(ep + 4);
            u.x = pack2bf(a.x, a.y); u.y = pack2bf(a.z, a.w);
            u.z = pack2bf(b.x, b.y); u.w = pack2bf(b.z, b.w);
        }
        evS[row * 8 + (g ^ (row & 7))] = u;
    }
}

__device__ inline void stage_qk(const float* __restrict__ ws, float (*qkS)[68],
                                int b, int m0, int n0, int tid) {
    for (int idx = tid; idx < 64 * 16; idx += 256) {
        const int row = idx >> 4, d4 = (idx & 15) * 4;
        const float* src = (row < 32)
            ? (ws + QW_OFF + ((size_t)(b * nS + m0 + row)) * nD + d4)
            : (ws + KW_OFF + ((size_t)(b * nS + n0 + (row - 32))) * nD + d4);
        const float4 v = *(const float4*)src;
        qkS[row][d4 + 0] = v.x; qkS[row][d4 + 1] = v.y;
        qkS[row][d4 + 2] = v.z; qkS[row][d4 + 3] = v.w;
    }
}

__device__ inline void build_U(const float (*qkS)[68], uint4* U, int si, int sj, int tid) {
    const float* qr = qkS[si * 16 + (tid >> 4)];
    const float* kr = qkS[32 + sj * 16 + (tid & 15)];
#pragma unroll
    for (int g = 0; g < 8; ++g) {
        uint4 u;
        u.x = pack2bf(qr[g*8+0]*kr[g*8+0], qr[g*8+1]*kr[g*8+1]);
        u.y = pack2bf(qr[g*8+2]*kr[g*8+2], qr[g*8+3]*kr[g*8+3]);
        u.z = pack2bf(qr[g*8+4]*kr[g*8+4], qr[g*8+5]*kr[g*8+5]);
        u.w = pack2bf(qr[g*8+6]*kr[g*8+6], qr[g*8+7]*kr[g*8+7]);
        U[tid * 8 + (g ^ (tid & 7))] = u;
    }
}

// ---------------- kS: einsum pass 1 -> per-(b,c) max only (sum is factorized) ----------------
__global__ __launch_bounds__(256) void kS_stats(float* __restrict__ ws)
{
    __shared__ uint4 evS[112 * 8];
    __shared__ uint4 U[256 * 8];
    __shared__ float qkS[64][68];
    __shared__ float mS[4][112];

    const int tid = threadIdx.x;
    const int b = blockIdx.y;
    const int m0 = (blockIdx.x >> 4) * 32, n0 = (blockIdx.x & 15) * 32;
    const int lane = tid & 63, w = tid >> 6;
    const int fr = lane & 15, fg = lane >> 4;

    stage_ev(ws, evS, tid);
    stage_qk(ws, qkS, b, m0, n0, tid);

    float pmax[28];
#pragma unroll
    for (int i = 0; i < 28; ++i) pmax[i] = -INFINITY;

    for (int st = 0; st < 4; ++st) {
        __syncthreads();
        build_U(qkS, U, st >> 1, st & 1, tid);
        __syncthreads();

        short8 uf[4][2];
#pragma unroll
        for (int nf = 0; nf < 4; ++nf)
#pragma unroll
            for (int ks = 0; ks < 2; ++ks) {
                const int row = w * 64 + nf * 16 + fr;
                UFrag u; u.u = U[row * 8 + ((ks * 4 + fg) ^ (row & 7))];
                uf[nf][ks] = u.s;
            }
#pragma unroll
        for (int cf = 0; cf < 7; ++cf) {
            short8 ef[2];
#pragma unroll
            for (int ks = 0; ks < 2; ++ks) {
                const int row = cf * 16 + fr;
                UFrag u; u.u = evS[row * 8 + ((ks * 4 + fg) ^ (row & 7))];
                ef[ks] = u.s;
            }
            f32x4 acc[4] = {};
#pragma unroll
            for (int ks = 0; ks < 2; ++ks)
#pragma unroll
                for (int nf = 0; nf < 4; ++nf)
                    acc[nf] = __builtin_amdgcn_mfma_f32_16x16x32_bf16(ef[ks], uf[nf][ks], acc[nf], 0, 0, 0);
#pragma unroll
            for (int nf = 0; nf < 4; ++nf)
#pragma unroll
                for (int r = 0; r < 4; ++r)
                    pmax[cf * 4 + r] = fmaxf(pmax[cf * 4 + r], acc[nf][r]);
        }
    }

    // reduce over the 16 mn-columns (low 4 lane bits)
#pragma unroll
    for (int i = 0; i < 28; ++i) {
#pragma unroll
        for (int off = 1; off < 16; off <<= 1)
            pmax[i] = fmaxf(pmax[i], __shfl_xor(pmax[i], off, 64));
    }
    if (fr == 0) {
#pragma unroll
        for (int cf = 0; cf < 7; ++cf)
#pragma unroll
            for (int r = 0; r < 4; ++r)
                mS[w][cf * 16 + fg * 4 + r] = pmax[cf * 4 + r];
    }
    __syncthreads();
    if (tid < nC) {
        const float mx = fmaxf(fmaxf(mS[0][tid], mS[1][tid]), fmaxf(mS[2][tid], mS[3][tid]));
        atomicMaxF(&ws[MAX_OFF + b * nC + tid], mx);
    }
}

// ---------------- kC: einsum pass 2 -> comp[b,{max,mean over c}] (inline MLP) ----------------
// avg from factored sum (SQK partials); strictly-lower tiles beyond conv halo skipped.
__global__ __launch_bounds__(256) void kC_comp(
    float* __restrict__ ws, const float* __restrict__ w1, const float* __restrict__ b1,
    const float* __restrict__ w2, const float* __restrict__ b2)
{
    __shared__ uint4 evS[112 * 8];
    __shared__ uint4 U[256 * 8];
    __shared__ float qkS[64][68];
    __shared__ float hS[12], scS[112];
    __shared__ float prodS[64], avgS[112];

    const int tid = threadIdx.x;
    const int b = blockIdx.y;
    const int m0 = (blockIdx.x >> 4) * 32, n0 = (blockIdx.x & 15) * 32;

    // comp only needed where some sig output (n >= (m>>7)<<7) can read it (3-halo)
    {
        const int mlo = m0 > 3 ? m0 - 3 : 0;
        const int ncut = ((mlo >> 7) << 7) - 3;
        if (n0 + 31 < ncut) return;        // blockIdx.x==0 never skipped
    }

    const int lane = tid & 63, w = tid >> 6;
    const int fr = lane & 15, fg = lane >> 4;

    if (tid < 64) {
        const float* p = ws + SQK_OFF + (size_t)b * 128 * 128;
        float sq = 0.f, sk = 0.f;
        for (int blk = 0; blk < 128; ++blk) {
            sq += p[blk * 128 + tid];
            sk += p[blk * 128 + 64 + tid];
        }
        prodS[tid] = sq * sk;
    }
    stage_ev(ws, evS, tid);
    stage_qk(ws, qkS, b, m0, n0, tid);
    __syncthreads();
    if (tid < nC) {   // avg[c] = (1/S^2) * sum_d ev[c,d]*Sq[d]*Sk[d]
        const float* ep = ws + EV_OFF + (size_t)tid * nD;
        float a = 0.f;
#pragma unroll 8
        for (int d = 0; d < nD; ++d) a += ep[d] * prodS[d];
        avgS[tid] = a * (1.f / (float)nSS);
    }
    __syncthreads();
    if (tid < 12) {
        const int src = tid / 6, j = tid % 6;
        float acc = b1[j];
        if (src == 0) {
            for (int cc = 0; cc < nC; ++cc) acc += avgS[cc] * w1[cc * 6 + j];
        } else {
            const float* v = ws + MAX_OFF + b * nC;
            for (int cc = 0; cc < nC; ++cc) acc += v[cc] * w1[cc * 6 + j];
        }
        hS[tid] = fmaxf(acc, 0.f);
    }
    __syncthreads();
    if (tid < 112) {
        float s = 0.f;
        if (tid < nC) {
            float acc = 2.f * b2[tid];
#pragma unroll
            for (int j = 0; j < 6; ++j) acc += (hS[j] + hS[6 + j]) * w2[j * nC + tid];
            s = 1.f / (1.f + expf(-acc));
            if (blockIdx.x == 0) ws[SCALE_OFF + b * nC + tid] = s;  // publish for k6
        }
        scS[tid] = s;
    }

    for (int st = 0; st < 4; ++st) {
        const int si = st >> 1, sj = st & 1;
        __syncthreads();
        build_U(qkS, U, si, sj, tid);
        __syncthreads();

        short8 uf[4][2];
#pragma unroll
        for (int nf = 0; nf < 4; ++nf)
#pragma unroll
            for (int ks = 0; ks < 2; ++ks) {
                const int row = w * 64 + nf * 16 + fr;
                UFrag u; u.u = U[row * 8 + ((ks * 4 + fg) ^ (row & 7))];
                uf[nf][ks] = u.s;
            }
        float mx[4], sm[4];
#pragma unroll
        for (int nf = 0; nf < 4; ++nf) { mx[nf] = -INFINITY; sm[nf] = 0.f; }
#pragma unroll
        for (int cf = 0; cf < 7; ++cf) {
            short8 ef[2];
#pragma unroll
            for (int ks = 0; ks < 2; ++ks) {
                const int row = cf * 16 + fr;
                UFrag u; u.u = evS[row * 8 + ((ks * 4 + fg) ^ (row & 7))];
                ef[ks] = u.s;
            }
            f32x4 acc[4] = {};
#pragma unroll
            for (int ks = 0; ks < 2; ++ks)
#pragma unroll
                for (int nf = 0; nf < 4; ++nf)
                    acc[nf] = __builtin_amdgcn_mfma_f32_16x16x32_bf16(ef[ks], uf[nf][ks], acc[nf], 0, 0, 0);
            const bool valid = (cf < 6) || (fg < 3);   // c < 108
#pragma unroll
            for (int nf = 0; nf < 4; ++nf)
#pragma unroll
                for (int r = 0; r < 4; ++r) {
                    const float v = scS[cf * 16 + fg * 4 + r] * acc[nf][r];
                    sm[nf] += v;
                    if (valid) mx[nf] = fmaxf(mx[nf], v);
                }
        }
#pragma unroll
        for (int nf = 0; nf < 4; ++nf) {
            mx[nf] = fmaxf(mx[nf], __shfl_xor(mx[nf], 16, 64));
            mx[nf] = fmaxf(mx[nf], __shfl_xor(mx[nf], 32, 64));
            sm[nf] += __shfl_xor(sm[nf], 16, 64);
            sm[nf] += __shfl_xor(sm[nf], 32, 64);
        }
        if (fg == 0) {
#pragma unroll
            for (int nf = 0; nf < 4; ++nf) {
                const int m = m0 + si * 16 + 4 * w + nf;
                const int n = n0 + sj * 16 + fr;
                ws[COMP_OFF + (((size_t)(b * 2 + 0)) * nS + m) * nS + n] = mx[nf];
                ws[COMP_OFF + (((size_t)(b * 2 + 1)) * nS + m) * nS + n] = sm[nf] * (1.f / (float)nC);
            }
        }
    }
}

// ---------------- K5: 7x7 conv on comp + sigmoid -> sig[b,m,n] (only n >= row's 128-block) ----------------
__global__ __launch_bounds__(512) void k5_conv(float* __restrict__ ws, const float* __restrict__ cw)
{
    __shared__ float S[14][520];
    __shared__ float wS[98];
    const int n = threadIdx.x;
    const int m = blockIdx.x & 511;
    const int b = blockIdx.x >> 9;
    const int n0q = (m >> 7) << 7;       // sig only consumed for n >= n0q
    const int c0 = n0q;                  // first staged S-column (compute reads cols >= n0q)
    const int W = 518 - c0;
    if (n < 98) wS[n] = cw[n];
    for (int idx = n; idx < 14 * W; idx += 512) {
        const int col = c0 + idx % W;
        const int r = idx / W;
        const int ch = r / 7, ky = r % 7;
        const int y = m + ky - 3;
        const int x = col - 3;
        float v = 0.f;
        if (y >= 0 && y < nS && x >= 0 && x < nS)
            v = ws[COMP_OFF + (((size_t)(b * 2 + ch)) * nS + y) * nS + x];
        S[r][col] = v;
    }
    __syncthreads();
    if (n >= n0q) {
        float acc = 0.f;
#pragma unroll
        for (int r = 0; r < 14; ++r)
#pragma unroll
            for (int kx = 0; kx < 7; ++kx)
                acc += S[r][n + kx] * wS[r * 7 + kx];
        acc *= 0.9999950000374997f;          // 1/sqrt(1+1e-5)
        ws[SIG_OFF + ((size_t)b * nS + m) * nS + n] = 1.f / (1.f + expf(-acc));
    }
}

// ---------------- staging + mfma helpers for k6 ----------------
__device__ inline void stage_tiles(const float* qwp, const float* kwp, const float* evp,
                                   uint4* ldsA, uint4* ldsB, int tid)
{
#pragma unroll
    for (int i = 0; i < 4; ++i) {
        const int q = tid + i * 256;
        const int row = q >> 3, g = q & 7;
        const int sw = row * 8 + (g ^ (row & 7));
        float4 x0 = *(const float4*)(qwp + row * nD + g * 8);
        float4 x1 = *(const float4*)(qwp + row * nD + g * 8 + 4);
        float4 e0 = *(const float4*)(evp + g * 8);
        float4 e1 = *(const float4*)(evp + g * 8 + 4);
        uint4 w;
        w.x = pack2bf(x0.x * e0.x, x0.y * e0.y);
        w.y = pack2bf(x0.z * e0.z, x0.w * e0.w);
        w.z = pack2bf(x1.x * e1.x, x1.y * e1.y);
        w.w = pack2bf(x1.z * e1.z, x1.w * e1.w);
        ldsA[sw] = w;
        float4 y0 = *(const float4*)(kwp + row * nD + g * 8);
        float4 y1 = *(const float4*)(kwp + row * nD + g * 8 + 4);
        uint4 v;
        v.x = pack2bf(y0.x, y0.y);
        v.y = pack2bf(y0.z, y0.w);
        v.z = pack2bf(y1.x, y1.y);
        v.w = pack2bf(y1.z, y1.w);
        ldsB[sw] = v;
    }
}

// diag: skip MFMAs for fragments that are strictly below the diagonal
__device__ inline void mfma_tile(const uint4* ldsA, const uint4* ldsB,
                                 int wr, int wc, int fr, int fg, bool diag, f32x4 acc[4][4])
{
#pragma unroll
    for (int ks = 0; ks < 2; ++ks) {
        short8 kf[4], qf[4];
#pragma unroll
        for (int i = 0; i < 4; ++i) {
            const int row = wc * 64 + i * 16 + fr;
            const int g = ks * 4 + fg;
            UFrag u; u.u = ldsB[row * 8 + (g ^ (row & 7))];
            kf[i] = u.s;
        }
#pragma unroll
        for (int j = 0; j < 4; ++j) {
            const int row = wr * 64 + j * 16 + fr;
            const int g = ks * 4 + fg;
            UFrag u; u.u = ldsA[row * 8 + (g ^ (row & 7))];
            qf[j] = u.s;
        }
#pragma unroll
        for (int i = 0; i < 4; ++i)
#pragma unroll
            for (int j = 0; j < 4; ++j)
                if (!diag || (wr * 64 + j * 16) <= (wc * 64 + i * 16))   // wave-uniform
                    acc[i][j] = __builtin_amdgcn_mfma_f32_16x16x32_bf16(kf[i], qf[j], acc[i][j], 0, 0, 0);
    }
}

// ---------------- K6: recompute einsum, apply (1+scale*sig), mask, tril, /8 ----------------
// Strictly-lower region: (x - 1e12) rounds to exactly -1e12 in fp32 (ULP=65536),
// so those outputs are the bit-exact constant -1e12/8 (or -inf under mask).
// Whole lower 128-tiles AND lower fragments of diagonal tiles take the fill path.
__global__ __launch_bounds__(256) void k6_final(
    float* __restrict__ ws, float* __restrict__ out, const int* __restrict__ mask)
{
    __shared__ uint4 ldsA[128 * 8];
    __shared__ uint4 ldsB[128 * 8];

    const int tid = threadIdx.x;
    const int mt = blockIdx.x >> 2, nt = blockIdx.x & 3;
    const int c  = blockIdx.y;
    const int b  = blockIdx.z;
    const int m0 = mt * 128, n0 = nt * 128;
    float* outb = out + (size_t)(b * nC + c) * nSS;
    const float CF = -1e12f * 0.125f;

    if (mt > nt) {   // strictly lower: constant fill, coalesced 512B/row per wave
        const int rr0 = tid >> 5;
        const int nn = n0 + (tid & 31) * 4;
        const int4 mc = *(const int4*)(mask + b * nS + nn);
#pragma unroll
        for (int p = 0; p < 16; ++p) {
            const int m = m0 + p * 8 + rr0;
            const int mr = mask[b * nS + m];
            float4 v;
            v.x = (mr && mc.x) ? CF : -INFINITY;
            v.y = (mr && mc.y) ? CF : -INFINITY;
            v.z = (mr && mc.z) ? CF : -INFINITY;
            v.w = (mr && mc.w) ? CF : -INFINITY;
            *(float4*)(outb + (size_t)m * nS + nn) = v;
        }
        return;
    }
    const bool diag = (mt == nt);

    stage_tiles(ws + QW_OFF + ((size_t)(b * nS + m0)) * nD,
                ws + KW_OFF + ((size_t)(b * nS + n0)) * nD,
                ws + EV_OFF + (size_t)c * nD, ldsA, ldsB, tid);
    __syncthreads();

    const int lane = tid & 63;
    const int wv = tid >> 6;
    const int wr = wv >> 1, wc = wv & 1;
    const int fr = lane & 15, fg = lane >> 4;

    f32x4 acc[4][4] = {};
    mfma_tile(ldsA, ldsB, wr, wc, fr, fg, diag, acc);

    const float scale = ws[SCALE_OFF + b * nC + c];
    const float* sig = ws + SIG_OFF + (size_t)b * nS * nS;

#pragma unroll
    for (int i = 0; i < 4; ++i) {
#pragma unroll
        for (int j = 0; j < 4; ++j) {
            const int m = m0 + wr * 64 + j * 16 + fr;
            const int nb = n0 + wc * 64 + i * 16 + fg * 4;
            const int mrow = mask[b * nS + m];
            const int4 mcol = *(const int4*)(mask + b * nS + nb);
            const int mcv[4] = { mcol.x, mcol.y, mcol.z, mcol.w };
            float r[4];
            if (diag && (wr * 64 + j * 16) > (wc * 64 + i * 16)) {
                // strictly-lower fragment of a diagonal tile: bit-exact constant
#pragma unroll
                for (int rr = 0; rr < 4; ++rr)
                    r[rr] = (mrow && mcv[rr]) ? CF : -INFINITY;
            } else {
                const float4 sg = *(const float4*)(sig + (size_t)m * nS + nb);
                const float sgv[4] = { sg.x, sg.y, sg.z, sg.w };
                const f32x4 a = acc[i][j];
#pragma unroll
                for (int rr = 0; rr < 4; ++rr) {
                    float v = a[rr] * (1.f + scale * sgv[rr]);
                    if (!mrow || !mcv[rr]) v = -INFINITY;
                    if (m > nb + rr) v -= 1e12f;
                    r[rr] = v * 0.125f;
                }
            }
            *(float4*)(outb + (size_t)m * nS + nb) = make_float4(r[0], r[1], r[2], r[3]);
        }
    }
}

extern "C" void kernel_launch(void* const* d_in, const int* in_sizes, int n_in,
                              void* d_out, int out_size, void* d_ws, size_t ws_size,
                              hipStream_t stream)
{
    const float* inputs = (const float*)d_in[0];
    const float* evin   = (const float*)d_in[1];
    const int*   mask   = (const int*)d_in[2];
    const float* wd     = (const float*)d_in[3];
    const float* bd     = (const float*)d_in[4];
    const float* we     = (const float*)d_in[5];
    const float* be     = (const float*)d_in[6];
    const float* w1     = (const float*)d_in[7];
    const float* b1     = (const float*)d_in[8];
    const float* w2     = (const float*)d_in[9];
    const float* b2     = (const float*)d_in[10];
    const float* cw     = (const float*)d_in[11];
    float* out = (float*)d_out;
    float* ws  = (float*)d_ws;

    k1_proj<<<256 + nC, 256, 0, stream>>>(inputs, evin, wd, bd, we, be, ws);
    kS_stats<<<dim3(256, nB), 256, 0, stream>>>(ws);
    kC_comp<<<dim3(256, nB), 256, 0, stream>>>(ws, w1, b1, w2, b2);
    k5_conv<<<nB * nS, 512, 0, stream>>>(ws, cw);
    k6_final<<<dim3(16, nC, nB), 256, 0, stream>>>(ws, out, mask);
}

// Round 3
// 157.527 us; speedup vs baseline: 1.0934x; 1.0221x over previous
//
#include <hip/hip_runtime.h>

// ---------------- problem constants ----------------
constexpr int nB = 2;       // batch
constexpr int nS = 512;     // seq len
constexpr int nH = 768;     // hidden
constexpr int nC = 108;     // channels
constexpr int nD = 64;      // head size
constexpr int nBC = nB * nC;          // 216
constexpr long long nSS = (long long)nS * nS;  // 262144

// ---------------- workspace layout (floats, in d_ws) ----------------
constexpr size_t QW_OFF    = 0;                         // 2*512*64 = 65536
constexpr size_t KW_OFF    = QW_OFF + (size_t)nB*nS*nD; // 65536
constexpr size_t EV_OFF    = KW_OFF + (size_t)nB*nS*nD; // 131072
constexpr size_t MAX_OFF   = EV_OFF + (size_t)nC*nD;    // 137984
constexpr size_t SCALE_OFF = MAX_OFF + nBC;             // 138200
constexpr size_t COMP_OFF  = SCALE_OFF + nBC;           // 138416
constexpr size_t SIG_OFF   = COMP_OFF + (size_t)nB*2*nS*nS;  // 1186992
// qw/kw per-block column-sum partials: [b][blk127][ {q:64, k:64} ] = 32768 floats.
// Aliases sig rows b=0,m=0..63 — written by k1, read by kC, overwritten by k5 before k6.
constexpr size_t SQK_OFF   = SIG_OFF;

typedef __attribute__((ext_vector_type(8))) short short8;
typedef __attribute__((ext_vector_type(4))) float f32x4;
union UFrag { uint4 u; short8 s; };

__device__ inline void atomicMaxF(float* addr, float v) {
    if (v >= 0.f) atomicMax((int*)addr, __float_as_int(v));
    else          atomicMin((unsigned int*)addr, __float_as_uint(v));
}

// round-to-nearest-even f32 -> bf16, packed pair
__device__ inline unsigned pack2bf(float a, float b) {
    unsigned ua = __float_as_uint(a), ub = __float_as_uint(b);
    ua = (ua + 0x7FFFu + ((ua >> 16) & 1u)) >> 16;
    ub = (ub + 0x7FFFu + ((ub >> 16) & 1u)) >> 16;
    return ua | (ub << 16);
}

// nontemporal float4 store (streaming output; keep sig/qw/kw L2-resident)
__device__ inline void ntstore4(float* p, float a, float b, float c, float d) {
    f32x4 v; v[0] = a; v[1] = b; v[2] = c; v[3] = d;
    __builtin_nontemporal_store(v, (f32x4*)p);
}

// ---------------- K1: seq = in@Wd+bd, RoPE -> qw,kw ; ev = evin@We+be ----------------
// 4 rows per block, k split across thread halves. Per-block qw/kw column-sum
// partials -> SQK (no atomics, no memset; deterministic).
__global__ __launch_bounds__(256) void k1_proj(
    const float* __restrict__ in, const float* __restrict__ evin,
    const float* __restrict__ wd, const float* __restrict__ bd,
    const float* __restrict__ we, const float* __restrict__ be,
    float* __restrict__ ws)
{
    __shared__ float rowT[nH][4];       // transposed rows: rowT[k][r], 12 KB
    __shared__ float accS[2][4][128];   // per-half partial sums
    __shared__ float ropeS[2][4][64];   // rope outputs for column-sum reduce
    const int blk = blockIdx.x, tid = threadIdx.x;
    if (blk == 0 && tid < nBC) ws[MAX_OFF + tid] = -INFINITY;
    if (blk < 256) {
        const int b = blk >> 7;
        const int m0 = (blk & 127) << 2;
        const float* src = in + ((size_t)(b * nS + m0)) * nH;
        for (int q = tid; q < 4 * nH; q += 256) {
            const int r = q / nH, k = q - r * nH;
            rowT[k][r] = src[q];
        }
        __syncthreads();
        const int h = tid >> 7, c = tid & 127;
        float a0 = h ? 0.f : bd[c], a1 = 0.f, a2 = 0.f, a3 = 0.f;
        const float* wp = wd + (size_t)(h * 384) * 128 + c;
        for (int k = h * 384; k < h * 384 + 384; ++k, wp += 128) {
            const float w = *wp;
            const float4 rv = *(const float4*)&rowT[k][0];
            a0 += rv.x * w; a1 += rv.y * w; a2 += rv.z * w; a3 += rv.w * w;
        }
        accS[h][0][c] = a0; accS[h][1][c] = a1; accS[h][2][c] = a2; accS[h][3][c] = a3;
        __syncthreads();
        const int r = tid >> 6, j = tid & 63;
        const int m = m0 + r;
        const int p = j >> 1;
        const float div = expf(-0.28782313662425572f * (float)p);
        const float ang = (float)m * div;
        const float co = cosf(ang), si = sinf(ang);
#pragma unroll
        for (int half = 0; half < 2; ++half) {
            const int i0 = half * 64 + (j & ~1);
            const int i1 = half * 64 + (j | 1);
            const float x0 = accS[0][r][i0] + accS[1][r][i0];
            const float x1 = accS[0][r][i1] + accS[1][r][i1];
            const float v = (j & 1) ? (x1 * co + x0 * si) : (x0 * co - x1 * si);
            ws[(half ? KW_OFF : QW_OFF) + ((size_t)(b * nS + m)) * nD + j] = v;
            ropeS[half][r][j] = v;
        }
        __syncthreads();
        if (tid < 128) {
            const int half = tid >> 6, jj = tid & 63;
            const float t = ropeS[half][0][jj] + ropeS[half][1][jj]
                          + ropeS[half][2][jj] + ropeS[half][3][jj];
            ws[SQK_OFF + ((size_t)(b * 128 + (blk & 127))) * 128 + half * 64 + jj] = t;
        }
    } else {
        const int ci = blk - 256;
        float* evrow = &rowT[0][0];   // flat 768 floats
        for (int k = tid; k < nH; k += 256) evrow[k] = evin[(size_t)ci * nH + k];
        __syncthreads();
        const int c = tid & 63, h = tid >> 6;   // 4 k-slices of 192
        float acc = 0.f;
        for (int k = h * 192; k < h * 192 + 192; ++k) acc += evrow[k] * we[k * nD + c];
        accS[0][h][c] = acc;
        __syncthreads();
        if (tid < nD) {
            const float s = be[tid] + accS[0][0][tid] + accS[0][1][tid]
                          + accS[0][2][tid] + accS[0][3][tid];
            ws[EV_OFF + (size_t)ci * nD + tid] = s;
        }
    }
}

// ======== shared machinery for the ev-as-A einsum (kS / kC) ========
__device__ inline void stage_ev(const float* __restrict__ ws, uint4* evS, int tid) {
    for (int idx = tid; idx < 112 * 8; idx += 256) {
        const int row = idx >> 3, g = idx & 7;
        uint4 u = make_uint4(0, 0, 0, 0);
        if (row < nC) {
            const float* ep = ws + EV_OFF + row * nD + g * 8;
            float4 a = *(const float4*)ep;
            float4 b = *(const float4*)(ep + 4);
            u.x = pack2bf(a.x, a.y); u.y = pack2bf(a.z, a.w);
            u.z = pack2bf(b.x, b.y); u.w = pack2bf(b.z, b.w);
        }
        evS[row * 8 + (g ^ (row & 7))] = u;
    }
}

__device__ inline void stage_qk(const float* __restrict__ ws, float (*qkS)[68],
                                int b, int m0, int n0, int tid) {
    for (int idx = tid; idx < 64 * 16; idx += 256) {
        const int row = idx >> 4, d4 = (idx & 15) * 4;
        const float* src = (row < 32)
            ? (ws + QW_OFF + ((size_t)(b * nS + m0 + row)) * nD + d4)
            : (ws + KW_OFF + ((size_t)(b * nS + n0 + (row - 32))) * nD + d4);
        const float4 v = *(const float4*)src;
        qkS[row][d4 + 0] = v.x; qkS[row][d4 + 1] = v.y;
        qkS[row][d4 + 2] = v.z; qkS[row][d4 + 3] = v.w;
    }
}

__device__ inline void build_U(const float (*qkS)[68], uint4* U, int si, int sj, int tid) {
    const float* qr = qkS[si * 16 + (tid >> 4)];
    const float* kr = qkS[32 + sj * 16 + (tid & 15)];
#pragma unroll
    for (int g = 0; g < 8; ++g) {
        uint4 u;
        u.x = pack2bf(qr[g*8+0]*kr[g*8+0], qr[g*8+1]*kr[g*8+1]);
        u.y = pack2bf(qr[g*8+2]*kr[g*8+2], qr[g*8+3]*kr[g*8+3]);
        u.z = pack2bf(qr[g*8+4]*kr[g*8+4], qr[g*8+5]*kr[g*8+5]);
        u.w = pack2bf(qr[g*8+6]*kr[g*8+6], qr[g*8+7]*kr[g*8+7]);
        U[tid * 8 + (g ^ (tid & 7))] = u;
    }
}

// ---------------- kS: einsum pass 1 -> per-(b,c) max only (sum is factorized) ----------------
__global__ __launch_bounds__(256) void kS_stats(float* __restrict__ ws)
{
    __shared__ uint4 evS[112 * 8];
    __shared__ uint4 U[256 * 8];
    __shared__ float qkS[64][68];
    __shared__ float mS[4][112];

    const int tid = threadIdx.x;
    const int b = blockIdx.y;
    const int m0 = (blockIdx.x >> 4) * 32, n0 = (blockIdx.x & 15) * 32;
    const int lane = tid & 63, w = tid >> 6;
    const int fr = lane & 15, fg = lane >> 4;

    stage_ev(ws, evS, tid);
    stage_qk(ws, qkS, b, m0, n0, tid);

    float pmax[28];
#pragma unroll
    for (int i = 0; i < 28; ++i) pmax[i] = -INFINITY;

    for (int st = 0; st < 4; ++st) {
        __syncthreads();
        build_U(qkS, U, st >> 1, st & 1, tid);
        __syncthreads();

        short8 uf[4][2];
#pragma unroll
        for (int nf = 0; nf < 4; ++nf)
#pragma unroll
            for (int ks = 0; ks < 2; ++ks) {
                const int row = w * 64 + nf * 16 + fr;
                UFrag u; u.u = U[row * 8 + ((ks * 4 + fg) ^ (row & 7))];
                uf[nf][ks] = u.s;
            }
#pragma unroll
        for (int cf = 0; cf < 7; ++cf) {
            short8 ef[2];
#pragma unroll
            for (int ks = 0; ks < 2; ++ks) {
                const int row = cf * 16 + fr;
                UFrag u; u.u = evS[row * 8 + ((ks * 4 + fg) ^ (row & 7))];
                ef[ks] = u.s;
            }
            f32x4 acc[4] = {};
#pragma unroll
            for (int ks = 0; ks < 2; ++ks)
#pragma unroll
                for (int nf = 0; nf < 4; ++nf)
                    acc[nf] = __builtin_amdgcn_mfma_f32_16x16x32_bf16(ef[ks], uf[nf][ks], acc[nf], 0, 0, 0);
#pragma unroll
            for (int nf = 0; nf < 4; ++nf)
#pragma unroll
                for (int r = 0; r < 4; ++r)
                    pmax[cf * 4 + r] = fmaxf(pmax[cf * 4 + r], acc[nf][r]);
        }
    }

    // reduce over the 16 mn-columns (low 4 lane bits)
#pragma unroll
    for (int i = 0; i < 28; ++i) {
#pragma unroll
        for (int off = 1; off < 16; off <<= 1)
            pmax[i] = fmaxf(pmax[i], __shfl_xor(pmax[i], off, 64));
    }
    if (fr == 0) {
#pragma unroll
        for (int cf = 0; cf < 7; ++cf)
#pragma unroll
            for (int r = 0; r < 4; ++r)
                mS[w][cf * 16 + fg * 4 + r] = pmax[cf * 4 + r];
    }
    __syncthreads();
    if (tid < nC) {
        const float mx = fmaxf(fmaxf(mS[0][tid], mS[1][tid]), fmaxf(mS[2][tid], mS[3][tid]));
        atomicMaxF(&ws[MAX_OFF + b * nC + tid], mx);
    }
}

// ---------------- kC: einsum pass 2 -> comp[b,{max,mean over c}] (inline MLP) ----------------
// avg from factored sum (SQK partials); strictly-lower tiles beyond conv halo skipped.
__global__ __launch_bounds__(256) void kC_comp(
    float* __restrict__ ws, const float* __restrict__ w1, const float* __restrict__ b1,
    const float* __restrict__ w2, const float* __restrict__ b2)
{
    __shared__ uint4 evS[112 * 8];
    __shared__ uint4 U[256 * 8];
    __shared__ float qkS[64][68];
    __shared__ float hS[12], scS[112];
    __shared__ float prodS[64], avgS[112];

    const int tid = threadIdx.x;
    const int b = blockIdx.y;
    const int m0 = (blockIdx.x >> 4) * 32, n0 = (blockIdx.x & 15) * 32;

    // comp only needed where some sig output (n >= (m>>7)<<7) can read it (3-halo)
    {
        const int mlo = m0 > 3 ? m0 - 3 : 0;
        const int ncut = ((mlo >> 7) << 7) - 3;
        if (n0 + 31 < ncut) return;        // blockIdx.x==0 never skipped
    }

    const int lane = tid & 63, w = tid >> 6;
    const int fr = lane & 15, fg = lane >> 4;

    if (tid < 64) {
        const float* p = ws + SQK_OFF + (size_t)b * 128 * 128;
        float sq = 0.f, sk = 0.f;
        for (int blk = 0; blk < 128; ++blk) {
            sq += p[blk * 128 + tid];
            sk += p[blk * 128 + 64 + tid];
        }
        prodS[tid] = sq * sk;
    }
    stage_ev(ws, evS, tid);
    stage_qk(ws, qkS, b, m0, n0, tid);
    __syncthreads();
    if (tid < nC) {   // avg[c] = (1/S^2) * sum_d ev[c,d]*Sq[d]*Sk[d]
        const float* ep = ws + EV_OFF + (size_t)tid * nD;
        float a = 0.f;
#pragma unroll 8
        for (int d = 0; d < nD; ++d) a += ep[d] * prodS[d];
        avgS[tid] = a * (1.f / (float)nSS);
    }
    __syncthreads();
    if (tid < 12) {
        const int src = tid / 6, j = tid % 6;
        float acc = b1[j];
        if (src == 0) {
            for (int cc = 0; cc < nC; ++cc) acc += avgS[cc] * w1[cc * 6 + j];
        } else {
            const float* v = ws + MAX_OFF + b * nC;
            for (int cc = 0; cc < nC; ++cc) acc += v[cc] * w1[cc * 6 + j];
        }
        hS[tid] = fmaxf(acc, 0.f);
    }
    __syncthreads();
    if (tid < 112) {
        float s = 0.f;
        if (tid < nC) {
            float acc = 2.f * b2[tid];
#pragma unroll
            for (int j = 0; j < 6; ++j) acc += (hS[j] + hS[6 + j]) * w2[j * nC + tid];
            s = 1.f / (1.f + expf(-acc));
            if (blockIdx.x == 0) ws[SCALE_OFF + b * nC + tid] = s;  // publish for k6
        }
        scS[tid] = s;
    }

    for (int st = 0; st < 4; ++st) {
        const int si = st >> 1, sj = st & 1;
        __syncthreads();
        build_U(qkS, U, si, sj, tid);
        __syncthreads();

        short8 uf[4][2];
#pragma unroll
        for (int nf = 0; nf < 4; ++nf)
#pragma unroll
            for (int ks = 0; ks < 2; ++ks) {
                const int row = w * 64 + nf * 16 + fr;
                UFrag u; u.u = U[row * 8 + ((ks * 4 + fg) ^ (row & 7))];
                uf[nf][ks] = u.s;
            }
        float mx[4], sm[4];
#pragma unroll
        for (int nf = 0; nf < 4; ++nf) { mx[nf] = -INFINITY; sm[nf] = 0.f; }
#pragma unroll
        for (int cf = 0; cf < 7; ++cf) {
            short8 ef[2];
#pragma unroll
            for (int ks = 0; ks < 2; ++ks) {
                const int row = cf * 16 + fr;
                UFrag u; u.u = evS[row * 8 + ((ks * 4 + fg) ^ (row & 7))];
                ef[ks] = u.s;
            }
            f32x4 acc[4] = {};
#pragma unroll
            for (int ks = 0; ks < 2; ++ks)
#pragma unroll
                for (int nf = 0; nf < 4; ++nf)
                    acc[nf] = __builtin_amdgcn_mfma_f32_16x16x32_bf16(ef[ks], uf[nf][ks], acc[nf], 0, 0, 0);
            const bool valid = (cf < 6) || (fg < 3);   // c < 108
#pragma unroll
            for (int nf = 0; nf < 4; ++nf)
#pragma unroll
                for (int r = 0; r < 4; ++r) {
                    const float v = scS[cf * 16 + fg * 4 + r] * acc[nf][r];
                    sm[nf] += v;
                    if (valid) mx[nf] = fmaxf(mx[nf], v);
                }
        }
#pragma unroll
        for (int nf = 0; nf < 4; ++nf) {
            mx[nf] = fmaxf(mx[nf], __shfl_xor(mx[nf], 16, 64));
            mx[nf] = fmaxf(mx[nf], __shfl_xor(mx[nf], 32, 64));
            sm[nf] += __shfl_xor(sm[nf], 16, 64);
            sm[nf] += __shfl_xor(sm[nf], 32, 64);
        }
        if (fg == 0) {
#pragma unroll
            for (int nf = 0; nf < 4; ++nf) {
                const int m = m0 + si * 16 + 4 * w + nf;
                const int n = n0 + sj * 16 + fr;
                ws[COMP_OFF + (((size_t)(b * 2 + 0)) * nS + m) * nS + n] = mx[nf];
                ws[COMP_OFF + (((size_t)(b * 2 + 1)) * nS + m) * nS + n] = sm[nf] * (1.f / (float)nC);
            }
        }
    }
}

// ---------------- K5: 7x7 conv on comp + sigmoid -> sig[b,m,n] (only n >= row's 128-block) ----------------
__global__ __launch_bounds__(512) void k5_conv(float* __restrict__ ws, const float* __restrict__ cw)
{
    __shared__ float S[14][520];
    __shared__ float wS[98];
    const int n = threadIdx.x;
    const int m = blockIdx.x & 511;
    const int b = blockIdx.x >> 9;
    const int n0q = (m >> 7) << 7;       // sig only consumed for n >= n0q
    const int c0 = n0q;                  // first staged S-column (compute reads cols >= n0q)
    const int W = 518 - c0;
    if (n < 98) wS[n] = cw[n];
    for (int idx = n; idx < 14 * W; idx += 512) {
        const int col = c0 + idx % W;
        const int r = idx / W;
        const int ch = r / 7, ky = r % 7;
        const int y = m + ky - 3;
        const int x = col - 3;
        float v = 0.f;
        if (y >= 0 && y < nS && x >= 0 && x < nS)
            v = ws[COMP_OFF + (((size_t)(b * 2 + ch)) * nS + y) * nS + x];
        S[r][col] = v;
    }
    __syncthreads();
    if (n >= n0q) {
        float acc = 0.f;
#pragma unroll
        for (int r = 0; r < 14; ++r)
#pragma unroll
            for (int kx = 0; kx < 7; ++kx)
                acc += S[r][n + kx] * wS[r * 7 + kx];
        acc *= 0.9999950000374997f;          // 1/sqrt(1+1e-5)
        ws[SIG_OFF + ((size_t)b * nS + m) * nS + n] = 1.f / (1.f + expf(-acc));
    }
}

// ---------------- staging + mfma helpers for k6 ----------------
__device__ inline void stage_tiles(const float* qwp, const float* kwp, const float* evp,
                                   uint4* ldsA, uint4* ldsB, int tid)
{
#pragma unroll
    for (int i = 0; i < 4; ++i) {
        const int q = tid + i * 256;
        const int row = q >> 3, g = q & 7;
        const int sw = row * 8 + (g ^ (row & 7));
        float4 x0 = *(const float4*)(qwp + row * nD + g * 8);
        float4 x1 = *(const float4*)(qwp + row * nD + g * 8 + 4);
        float4 e0 = *(const float4*)(evp + g * 8);
        float4 e1 = *(const float4*)(evp + g * 8 + 4);
        uint4 w;
        w.x = pack2bf(x0.x * e0.x, x0.y * e0.y);
        w.y = pack2bf(x0.z * e0.z, x0.w * e0.w);
        w.z = pack2bf(x1.x * e1.x, x1.y * e1.y);
        w.w = pack2bf(x1.z * e1.z, x1.w * e1.w);
        ldsA[sw] = w;
        float4 y0 = *(const float4*)(kwp + row * nD + g * 8);
        float4 y1 = *(const float4*)(kwp + row * nD + g * 8 + 4);
        uint4 v;
        v.x = pack2bf(y0.x, y0.y);
        v.y = pack2bf(y0.z, y0.w);
        v.z = pack2bf(y1.x, y1.y);
        v.w = pack2bf(y1.z, y1.w);
        ldsB[sw] = v;
    }
}

// diag: skip MFMAs for fragments that are strictly below the diagonal
__device__ inline void mfma_tile(const uint4* ldsA, const uint4* ldsB,
                                 int wr, int wc, int fr, int fg, bool diag, f32x4 acc[4][4])
{
#pragma unroll
    for (int ks = 0; ks < 2; ++ks) {
        short8 kf[4], qf[4];
#pragma unroll
        for (int i = 0; i < 4; ++i) {
            const int row = wc * 64 + i * 16 + fr;
            const int g = ks * 4 + fg;
            UFrag u; u.u = ldsB[row * 8 + (g ^ (row & 7))];
            kf[i] = u.s;
        }
#pragma unroll
        for (int j = 0; j < 4; ++j) {
            const int row = wr * 64 + j * 16 + fr;
            const int g = ks * 4 + fg;
            UFrag u; u.u = ldsA[row * 8 + (g ^ (row & 7))];
            qf[j] = u.s;
        }
#pragma unroll
        for (int i = 0; i < 4; ++i)
#pragma unroll
            for (int j = 0; j < 4; ++j)
                if (!diag || (wr * 64 + j * 16) <= (wc * 64 + i * 16))   // wave-uniform
                    acc[i][j] = __builtin_amdgcn_mfma_f32_16x16x32_bf16(kf[i], qf[j], acc[i][j], 0, 0, 0);
    }
}

// ---------------- K6: recompute einsum, apply (1+scale*sig), mask, tril, /8 ----------------
// Strictly-lower region: (x - 1e12) rounds to exactly -1e12 in fp32 (ULP=65536),
// so those outputs are the bit-exact constant -1e12/8 (or -inf under mask).
// Whole lower 128-tiles AND lower fragments of diagonal tiles take the fill path.
// All out-stores are nontemporal: protect L2-resident sig/qw/kw/ev from eviction.
__global__ __launch_bounds__(256) void k6_final(
    float* __restrict__ ws, float* __restrict__ out, const int* __restrict__ mask)
{
    __shared__ uint4 ldsA[128 * 8];
    __shared__ uint4 ldsB[128 * 8];

    const int tid = threadIdx.x;
    const int mt = blockIdx.x >> 2, nt = blockIdx.x & 3;
    const int c  = blockIdx.y;
    const int b  = blockIdx.z;
    const int m0 = mt * 128, n0 = nt * 128;
    float* outb = out + (size_t)(b * nC + c) * nSS;
    const float CF = -1e12f * 0.125f;

    if (mt > nt) {   // strictly lower: constant fill, coalesced 512B/row per wave
        const int rr0 = tid >> 5;
        const int nn = n0 + (tid & 31) * 4;
        const int4 mc = *(const int4*)(mask + b * nS + nn);
#pragma unroll
        for (int p = 0; p < 16; ++p) {
            const int m = m0 + p * 8 + rr0;
            const int mr = mask[b * nS + m];
            ntstore4(outb + (size_t)m * nS + nn,
                     (mr && mc.x) ? CF : -INFINITY,
                     (mr && mc.y) ? CF : -INFINITY,
                     (mr && mc.z) ? CF : -INFINITY,
                     (mr && mc.w) ? CF : -INFINITY);
        }
        return;
    }
    const bool diag = (mt == nt);

    stage_tiles(ws + QW_OFF + ((size_t)(b * nS + m0)) * nD,
                ws + KW_OFF + ((size_t)(b * nS + n0)) * nD,
                ws + EV_OFF + (size_t)c * nD, ldsA, ldsB, tid);
    __syncthreads();

    const int lane = tid & 63;
    const int wv = tid >> 6;
    const int wr = wv >> 1, wc = wv & 1;
    const int fr = lane & 15, fg = lane >> 4;

    f32x4 acc[4][4] = {};
    mfma_tile(ldsA, ldsB, wr, wc, fr, fg, diag, acc);

    const float scale = ws[SCALE_OFF + b * nC + c];
    const float* sig = ws + SIG_OFF + (size_t)b * nS * nS;

#pragma unroll
    for (int i = 0; i < 4; ++i) {
#pragma unroll
        for (int j = 0; j < 4; ++j) {
            const int m = m0 + wr * 64 + j * 16 + fr;
            const int nb = n0 + wc * 64 + i * 16 + fg * 4;
            const int mrow = mask[b * nS + m];
            const int4 mcol = *(const int4*)(mask + b * nS + nb);
            const int mcv[4] = { mcol.x, mcol.y, mcol.z, mcol.w };
            float r[4];
            if (diag && (wr * 64 + j * 16) > (wc * 64 + i * 16)) {
                // strictly-lower fragment of a diagonal tile: bit-exact constant
#pragma unroll
                for (int rr = 0; rr < 4; ++rr)
                    r[rr] = (mrow && mcv[rr]) ? CF : -INFINITY;
            } else {
                const float4 sg = *(const float4*)(sig + (size_t)m * nS + nb);
                const float sgv[4] = { sg.x, sg.y, sg.z, sg.w };
                const f32x4 a = acc[i][j];
#pragma unroll
                for (int rr = 0; rr < 4; ++rr) {
                    float v = a[rr] * (1.f + scale * sgv[rr]);
                    if (!mrow || !mcv[rr]) v = -INFINITY;
                    if (m > nb + rr) v -= 1e12f;
                    r[rr] = v * 0.125f;
                }
            }
            ntstore4(outb + (size_t)m * nS + nb, r[0], r[1], r[2], r[3]);
        }
    }
}

extern "C" void kernel_launch(void* const* d_in, const int* in_sizes, int n_in,
                              void* d_out, int out_size, void* d_ws, size_t ws_size,
                              hipStream_t stream)
{
    const float* inputs = (const float*)d_in[0];
    const float* evin   = (const float*)d_in[1];
    const int*   mask   = (const int*)d_in[2];
    const float* wd     = (const float*)d_in[3];
    const float* bd     = (const float*)d_in[4];
    const float* we     = (const float*)d_in[5];
    const float* be     = (const float*)d_in[6];
    const float* w1     = (const float*)d_in[7];
    const float* b1     = (const float*)d_in[8];
    const float* w2     = (const float*)d_in[9];
    const float* b2     = (const float*)d_in[10];
    const float* cw     = (const float*)d_in[11];
    float* out = (float*)d_out;
    float* ws  = (float*)d_ws;

    k1_proj<<<256 + nC, 256, 0, stream>>>(inputs, evin, wd, bd, we, be, ws);
    kS_stats<<<dim3(256, nB), 256, 0, stream>>>(ws);
    kC_comp<<<dim3(256, nB), 256, 0, stream>>>(ws, w1, b1, w2, b2);
    k5_conv<<<nB * nS, 512, 0, stream>>>(ws, cw);
    k6_final<<<dim3(16, nC, nB), 256, 0, stream>>>(ws, out, mask);
}

// Round 4
// 155.345 us; speedup vs baseline: 1.1088x; 1.0140x over previous
//
#include <hip/hip_runtime.h>
#include <hip/hip_bf16.h>

// ---------------- problem constants ----------------
constexpr int nB = 2;       // batch
constexpr int nS = 512;     // seq len
constexpr int nH = 768;     // hidden
constexpr int nC = 108;     // channels
constexpr int nD = 64;      // head size
constexpr int nBC = nB * nC;          // 216
constexpr long long nSS = (long long)nS * nS;  // 262144

// ---------------- workspace layout (floats, in d_ws) ----------------
constexpr size_t QW_OFF    = 0;                         // 2*512*64 = 65536
constexpr size_t KW_OFF    = QW_OFF + (size_t)nB*nS*nD; // 65536
constexpr size_t EV_OFF    = KW_OFF + (size_t)nB*nS*nD; // 131072
constexpr size_t MAX_OFF   = EV_OFF + (size_t)nC*nD;    // 137984
constexpr size_t SCALE_OFF = MAX_OFF + nBC;             // 138200
constexpr size_t COMP_OFF  = SCALE_OFF + nBC;           // 138416
constexpr size_t SIG_OFF   = COMP_OFF + (size_t)nB*2*nS*nS;  // 1186992
// qw/kw per-block column-sum partials: [b][blk127][ {q:64, k:64} ] = 32768 floats.
// Aliases sig rows b=0,m=0..63 — written by k1, read by kC, overwritten by k5 before k6.
constexpr size_t SQK_OFF   = SIG_OFF;

typedef __attribute__((ext_vector_type(8))) short short8;
typedef __attribute__((ext_vector_type(4))) float f32x4;
union UFrag { uint4 u; short8 s; };

__device__ inline void atomicMaxF(float* addr, float v) {
    if (v >= 0.f) atomicMax((int*)addr, __float_as_int(v));
    else          atomicMin((unsigned int*)addr, __float_as_uint(v));
}

// f32 pair -> packed bf16 (RNE). Scalar-cast form lets the compiler select
// the HW v_cvt_pk_bf16_f32 (gfx950) instead of ~9-op bit-twiddle emulation.
__device__ inline unsigned pack2bf(float a, float b) {
    __hip_bfloat162 h = __float22bfloat162_rn(float2{a, b});
    union { __hip_bfloat162 h2; unsigned u; } cv;
    cv.h2 = h;
    return cv.u;
}

// nontemporal float4 store (streaming output; keep sig/qw/kw L2-resident)
__device__ inline void ntstore4(float* p, float a, float b, float c, float d) {
    f32x4 v; v[0] = a; v[1] = b; v[2] = c; v[3] = d;
    __builtin_nontemporal_store(v, (f32x4*)p);
}

// ---------------- K1: seq = in@Wd+bd, RoPE -> qw,kw ; ev = evin@We+be ----------------
// 4 rows per block, k split across thread halves. Per-block qw/kw column-sum
// partials -> SQK (no atomics, no memset; deterministic).
__global__ __launch_bounds__(256) void k1_proj(
    const float* __restrict__ in, const float* __restrict__ evin,
    const float* __restrict__ wd, const float* __restrict__ bd,
    const float* __restrict__ we, const float* __restrict__ be,
    float* __restrict__ ws)
{
    __shared__ float rowT[nH][4];       // transposed rows: rowT[k][r], 12 KB
    __shared__ float accS[2][4][128];   // per-half partial sums
    __shared__ float ropeS[2][4][64];   // rope outputs for column-sum reduce
    const int blk = blockIdx.x, tid = threadIdx.x;
    if (blk == 0 && tid < nBC) ws[MAX_OFF + tid] = -INFINITY;
    if (blk < 256) {
        const int b = blk >> 7;
        const int m0 = (blk & 127) << 2;
        const float* src = in + ((size_t)(b * nS + m0)) * nH;
        for (int q = tid; q < 4 * nH; q += 256) {
            const int r = q / nH, k = q - r * nH;
            rowT[k][r] = src[q];
        }
        __syncthreads();
        const int h = tid >> 7, c = tid & 127;
        float a0 = h ? 0.f : bd[c], a1 = 0.f, a2 = 0.f, a3 = 0.f;
        const float* wp = wd + (size_t)(h * 384) * 128 + c;
        for (int k = h * 384; k < h * 384 + 384; ++k, wp += 128) {
            const float w = *wp;
            const float4 rv = *(const float4*)&rowT[k][0];
            a0 += rv.x * w; a1 += rv.y * w; a2 += rv.z * w; a3 += rv.w * w;
        }
        accS[h][0][c] = a0; accS[h][1][c] = a1; accS[h][2][c] = a2; accS[h][3][c] = a3;
        __syncthreads();
        const int r = tid >> 6, j = tid & 63;
        const int m = m0 + r;
        const int p = j >> 1;
        const float div = expf(-0.28782313662425572f * (float)p);
        const float ang = (float)m * div;
        const float co = cosf(ang), si = sinf(ang);
#pragma unroll
        for (int half = 0; half < 2; ++half) {
            const int i0 = half * 64 + (j & ~1);
            const int i1 = half * 64 + (j | 1);
            const float x0 = accS[0][r][i0] + accS[1][r][i0];
            const float x1 = accS[0][r][i1] + accS[1][r][i1];
            const float v = (j & 1) ? (x1 * co + x0 * si) : (x0 * co - x1 * si);
            ws[(half ? KW_OFF : QW_OFF) + ((size_t)(b * nS + m)) * nD + j] = v;
            ropeS[half][r][j] = v;
        }
        __syncthreads();
        if (tid < 128) {
            const int half = tid >> 6, jj = tid & 63;
            const float t = ropeS[half][0][jj] + ropeS[half][1][jj]
                          + ropeS[half][2][jj] + ropeS[half][3][jj];
            ws[SQK_OFF + ((size_t)(b * 128 + (blk & 127))) * 128 + half * 64 + jj] = t;
        }
    } else {
        const int ci = blk - 256;
        float* evrow = &rowT[0][0];   // flat 768 floats
        for (int k = tid; k < nH; k += 256) evrow[k] = evin[(size_t)ci * nH + k];
        __syncthreads();
        const int c = tid & 63, h = tid >> 6;   // 4 k-slices of 192
        float acc = 0.f;
        for (int k = h * 192; k < h * 192 + 192; ++k) acc += evrow[k] * we[k * nD + c];
        accS[0][h][c] = acc;
        __syncthreads();
        if (tid < nD) {
            const float s = be[tid] + accS[0][0][tid] + accS[0][1][tid]
                          + accS[0][2][tid] + accS[0][3][tid];
            ws[EV_OFF + (size_t)ci * nD + tid] = s;
        }
    }
}

// ======== shared machinery for the ev-as-A einsum (kS / kC) ========
__device__ inline void stage_ev(const float* __restrict__ ws, uint4* evS, int tid) {
    for (int idx = tid; idx < 112 * 8; idx += 256) {
        const int row = idx >> 3, g = idx & 7;
        uint4 u = make_uint4(0, 0, 0, 0);
        if (row < nC) {
            const float* ep = ws + EV_OFF + row * nD + g * 8;
            float4 a = *(const float4*)ep;
            float4 b = *(const float4*)(ep + 4);
            u.x = pack2bf(a.x, a.y); u.y = pack2bf(a.z, a.w);
            u.z = pack2bf(b.x, b.y); u.w = pack2bf(b.z, b.w);
        }
        evS[row * 8 + (g ^ (row & 7))] = u;
    }
}

__device__ inline void stage_qk(const float* __restrict__ ws, float (*qkS)[68],
                                int b, int m0, int n0, int tid) {
    for (int idx = tid; idx < 64 * 16; idx += 256) {
        const int row = idx >> 4, d4 = (idx & 15) * 4;
        const float* src = (row < 32)
            ? (ws + QW_OFF + ((size_t)(b * nS + m0 + row)) * nD + d4)
            : (ws + KW_OFF + ((size_t)(b * nS + n0 + (row - 32))) * nD + d4);
        const float4 v = *(const float4*)src;
        qkS[row][d4 + 0] = v.x; qkS[row][d4 + 1] = v.y;
        qkS[row][d4 + 2] = v.z; qkS[row][d4 + 3] = v.w;
    }
}

__device__ inline void build_U(const float (*qkS)[68], uint4* U, int si, int sj, int tid) {
    const float* qr = qkS[si * 16 + (tid >> 4)];
    const float* kr = qkS[32 + sj * 16 + (tid & 15)];
#pragma unroll
    for (int g = 0; g < 8; ++g) {
        uint4 u;
        u.x = pack2bf(qr[g*8+0]*kr[g*8+0], qr[g*8+1]*kr[g*8+1]);
        u.y = pack2bf(qr[g*8+2]*kr[g*8+2], qr[g*8+3]*kr[g*8+3]);
        u.z = pack2bf(qr[g*8+4]*kr[g*8+4], qr[g*8+5]*kr[g*8+5]);
        u.w = pack2bf(qr[g*8+6]*kr[g*8+6], qr[g*8+7]*kr[g*8+7]);
        U[tid * 8 + (g ^ (tid & 7))] = u;
    }
}

// ---------------- kS: einsum pass 1 -> per-(b,c) max only (sum is factorized) ----------------
__global__ __launch_bounds__(256) void kS_stats(float* __restrict__ ws)
{
    __shared__ uint4 evS[112 * 8];
    __shared__ uint4 U[256 * 8];
    __shared__ float qkS[64][68];
    __shared__ float mS[4][112];

    const int tid = threadIdx.x;
    const int b = blockIdx.y;
    const int m0 = (blockIdx.x >> 4) * 32, n0 = (blockIdx.x & 15) * 32;
    const int lane = tid & 63, w = tid >> 6;
    const int fr = lane & 15, fg = lane >> 4;

    stage_ev(ws, evS, tid);
    stage_qk(ws, qkS, b, m0, n0, tid);

    float pmax[28];
#pragma unroll
    for (int i = 0; i < 28; ++i) pmax[i] = -INFINITY;

    for (int st = 0; st < 4; ++st) {
        __syncthreads();
        build_U(qkS, U, st >> 1, st & 1, tid);
        __syncthreads();

        short8 uf[4][2];
#pragma unroll
        for (int nf = 0; nf < 4; ++nf)
#pragma unroll
            for (int ks = 0; ks < 2; ++ks) {
                const int row = w * 64 + nf * 16 + fr;
                UFrag u; u.u = U[row * 8 + ((ks * 4 + fg) ^ (row & 7))];
                uf[nf][ks] = u.s;
            }
#pragma unroll
        for (int cf = 0; cf < 7; ++cf) {
            short8 ef[2];
#pragma unroll
            for (int ks = 0; ks < 2; ++ks) {
                const int row = cf * 16 + fr;
                UFrag u; u.u = evS[row * 8 + ((ks * 4 + fg) ^ (row & 7))];
                ef[ks] = u.s;
            }
            f32x4 acc[4] = {};
#pragma unroll
            for (int ks = 0; ks < 2; ++ks)
#pragma unroll
                for (int nf = 0; nf < 4; ++nf)
                    acc[nf] = __builtin_amdgcn_mfma_f32_16x16x32_bf16(ef[ks], uf[nf][ks], acc[nf], 0, 0, 0);
#pragma unroll
            for (int nf = 0; nf < 4; ++nf)
#pragma unroll
                for (int r = 0; r < 4; ++r)
                    pmax[cf * 4 + r] = fmaxf(pmax[cf * 4 + r], acc[nf][r]);
        }
    }

    // reduce over the 16 mn-columns (low 4 lane bits)
#pragma unroll
    for (int i = 0; i < 28; ++i) {
#pragma unroll
        for (int off = 1; off < 16; off <<= 1)
            pmax[i] = fmaxf(pmax[i], __shfl_xor(pmax[i], off, 64));
    }
    if (fr == 0) {
#pragma unroll
        for (int cf = 0; cf < 7; ++cf)
#pragma unroll
            for (int r = 0; r < 4; ++r)
                mS[w][cf * 16 + fg * 4 + r] = pmax[cf * 4 + r];
    }
    __syncthreads();
    if (tid < nC) {
        const float mx = fmaxf(fmaxf(mS[0][tid], mS[1][tid]), fmaxf(mS[2][tid], mS[3][tid]));
        atomicMaxF(&ws[MAX_OFF + b * nC + tid], mx);
    }
}

// ---------------- kC: einsum pass 2 -> comp[b,{max,mean over c}] (inline MLP) ----------------
// avg from factored sum (SQK partials); strictly-lower tiles beyond conv halo skipped.
__global__ __launch_bounds__(256) void kC_comp(
    float* __restrict__ ws, const float* __restrict__ w1, const float* __restrict__ b1,
    const float* __restrict__ w2, const float* __restrict__ b2)
{
    __shared__ uint4 evS[112 * 8];
    __shared__ uint4 U[256 * 8];
    __shared__ float qkS[64][68];
    __shared__ float hS[12], scS[112];
    __shared__ float prodS[64], avgS[112];

    const int tid = threadIdx.x;
    const int b = blockIdx.y;
    const int m0 = (blockIdx.x >> 4) * 32, n0 = (blockIdx.x & 15) * 32;

    // comp only needed where some sig output (n >= (m>>7)<<7) can read it (3-halo)
    {
        const int mlo = m0 > 3 ? m0 - 3 : 0;
        const int ncut = ((mlo >> 7) << 7) - 3;
        if (n0 + 31 < ncut) return;        // blockIdx.x==0 never skipped
    }

    const int lane = tid & 63, w = tid >> 6;
    const int fr = lane & 15, fg = lane >> 4;

    if (tid < 64) {
        const float* p = ws + SQK_OFF + (size_t)b * 128 * 128;
        float sq = 0.f, sk = 0.f;
        for (int blk = 0; blk < 128; ++blk) {
            sq += p[blk * 128 + tid];
            sk += p[blk * 128 + 64 + tid];
        }
        prodS[tid] = sq * sk;
    }
    stage_ev(ws, evS, tid);
    stage_qk(ws, qkS, b, m0, n0, tid);
    __syncthreads();
    if (tid < nC) {   // avg[c] = (1/S^2) * sum_d ev[c,d]*Sq[d]*Sk[d]
        const float* ep = ws + EV_OFF + (size_t)tid * nD;
        float a = 0.f;
#pragma unroll 8
        for (int d = 0; d < nD; ++d) a += ep[d] * prodS[d];
        avgS[tid] = a * (1.f / (float)nSS);
    }
    __syncthreads();
    if (tid < 12) {
        const int src = tid / 6, j = tid % 6;
        float acc = b1[j];
        if (src == 0) {
            for (int cc = 0; cc < nC; ++cc) acc += avgS[cc] * w1[cc * 6 + j];
        } else {
            const float* v = ws + MAX_OFF + b * nC;
            for (int cc = 0; cc < nC; ++cc) acc += v[cc] * w1[cc * 6 + j];
        }
        hS[tid] = fmaxf(acc, 0.f);
    }
    __syncthreads();
    if (tid < 112) {
        float s = 0.f;
        if (tid < nC) {
            float acc = 2.f * b2[tid];
#pragma unroll
            for (int j = 0; j < 6; ++j) acc += (hS[j] + hS[6 + j]) * w2[j * nC + tid];
            s = 1.f / (1.f + expf(-acc));
            if (blockIdx.x == 0) ws[SCALE_OFF + b * nC + tid] = s;  // publish for k6
        }
        scS[tid] = s;
    }

    for (int st = 0; st < 4; ++st) {
        const int si = st >> 1, sj = st & 1;
        __syncthreads();
        build_U(qkS, U, si, sj, tid);
        __syncthreads();

        short8 uf[4][2];
#pragma unroll
        for (int nf = 0; nf < 4; ++nf)
#pragma unroll
            for (int ks = 0; ks < 2; ++ks) {
                const int row = w * 64 + nf * 16 + fr;
                UFrag u; u.u = U[row * 8 + ((ks * 4 + fg) ^ (row & 7))];
                uf[nf][ks] = u.s;
            }
        float mx[4], sm[4];
#pragma unroll
        for (int nf = 0; nf < 4; ++nf) { mx[nf] = -INFINITY; sm[nf] = 0.f; }
#pragma unroll
        for (int cf = 0; cf < 7; ++cf) {
            short8 ef[2];
#pragma unroll
            for (int ks = 0; ks < 2; ++ks) {
                const int row = cf * 16 + fr;
                UFrag u; u.u = evS[row * 8 + ((ks * 4 + fg) ^ (row & 7))];
                ef[ks] = u.s;
            }
            f32x4 acc[4] = {};
#pragma unroll
            for (int ks = 0; ks < 2; ++ks)
#pragma unroll
                for (int nf = 0; nf < 4; ++nf)
                    acc[nf] = __builtin_amdgcn_mfma_f32_16x16x32_bf16(ef[ks], uf[nf][ks], acc[nf], 0, 0, 0);
            const bool valid = (cf < 6) || (fg < 3);   // c < 108
#pragma unroll
            for (int nf = 0; nf < 4; ++nf)
#pragma unroll
                for (int r = 0; r < 4; ++r) {
                    const float v = scS[cf * 16 + fg * 4 + r] * acc[nf][r];
                    sm[nf] += v;
                    if (valid) mx[nf] = fmaxf(mx[nf], v);
                }
        }
#pragma unroll
        for (int nf = 0; nf < 4; ++nf) {
            mx[nf] = fmaxf(mx[nf], __shfl_xor(mx[nf], 16, 64));
            mx[nf] = fmaxf(mx[nf], __shfl_xor(mx[nf], 32, 64));
            sm[nf] += __shfl_xor(sm[nf], 16, 64);
            sm[nf] += __shfl_xor(sm[nf], 32, 64);
        }
        if (fg == 0) {
#pragma unroll
            for (int nf = 0; nf < 4; ++nf) {
                const int m = m0 + si * 16 + 4 * w + nf;
                const int n = n0 + sj * 16 + fr;
                ws[COMP_OFF + (((size_t)(b * 2 + 0)) * nS + m) * nS + n] = mx[nf];
                ws[COMP_OFF + (((size_t)(b * 2 + 1)) * nS + m) * nS + n] = sm[nf] * (1.f / (float)nC);
            }
        }
    }
}

// ---------------- K5: 7x7 conv on comp + sigmoid -> sig[b,m,n] (only n >= row's 128-block) ----------------
__global__ __launch_bounds__(512) void k5_conv(float* __restrict__ ws, const float* __restrict__ cw)
{
    __shared__ float S[14][520];
    __shared__ float wS[98];
    const int n = threadIdx.x;
    const int m = blockIdx.x & 511;
    const int b = blockIdx.x >> 9;
    const int n0q = (m >> 7) << 7;       // sig only consumed for n >= n0q
    const int c0 = n0q;                  // first staged S-column (compute reads cols >= n0q)
    const int W = 518 - c0;
    if (n < 98) wS[n] = cw[n];
    for (int idx = n; idx < 14 * W; idx += 512) {
        const int col = c0 + idx % W;
        const int r = idx / W;
        const int ch = r / 7, ky = r % 7;
        const int y = m + ky - 3;
        const int x = col - 3;
        float v = 0.f;
        if (y >= 0 && y < nS && x >= 0 && x < nS)
            v = ws[COMP_OFF + (((size_t)(b * 2 + ch)) * nS + y) * nS + x];
        S[r][col] = v;
    }
    __syncthreads();
    if (n >= n0q) {
        float acc = 0.f;
#pragma unroll
        for (int r = 0; r < 14; ++r)
#pragma unroll
            for (int kx = 0; kx < 7; ++kx)
                acc += S[r][n + kx] * wS[r * 7 + kx];
        acc *= 0.9999950000374997f;          // 1/sqrt(1+1e-5)
        ws[SIG_OFF + ((size_t)b * nS + m) * nS + n] = 1.f / (1.f + expf(-acc));
    }
}

// ---------------- staging + mfma helpers for k6 ----------------
__device__ inline void stage_tiles(const float* qwp, const float* kwp, const float* evp,
                                   uint4* ldsA, uint4* ldsB, int tid)
{
#pragma unroll
    for (int i = 0; i < 4; ++i) {
        const int q = tid + i * 256;
        const int row = q >> 3, g = q & 7;
        const int sw = row * 8 + (g ^ (row & 7));
        float4 x0 = *(const float4*)(qwp + row * nD + g * 8);
        float4 x1 = *(const float4*)(qwp + row * nD + g * 8 + 4);
        float4 e0 = *(const float4*)(evp + g * 8);
        float4 e1 = *(const float4*)(evp + g * 8 + 4);
        uint4 w;
        w.x = pack2bf(x0.x * e0.x, x0.y * e0.y);
        w.y = pack2bf(x0.z * e0.z, x0.w * e0.w);
        w.z = pack2bf(x1.x * e1.x, x1.y * e1.y);
        w.w = pack2bf(x1.z * e1.z, x1.w * e1.w);
        ldsA[sw] = w;
        float4 y0 = *(const float4*)(kwp + row * nD + g * 8);
        float4 y1 = *(const float4*)(kwp + row * nD + g * 8 + 4);
        uint4 v;
        v.x = pack2bf(y0.x, y0.y);
        v.y = pack2bf(y0.z, y0.w);
        v.z = pack2bf(y1.x, y1.y);
        v.w = pack2bf(y1.z, y1.w);
        ldsB[sw] = v;
    }
}

// diag: skip MFMAs for fragments that are strictly below the diagonal
__device__ inline void mfma_tile(const uint4* ldsA, const uint4* ldsB,
                                 int wr, int wc, int fr, int fg, bool diag, f32x4 acc[4][4])
{
#pragma unroll
    for (int ks = 0; ks < 2; ++ks) {
        short8 kf[4], qf[4];
#pragma unroll
        for (int i = 0; i < 4; ++i) {
            const int row = wc * 64 + i * 16 + fr;
            const int g = ks * 4 + fg;
            UFrag u; u.u = ldsB[row * 8 + (g ^ (row & 7))];
            kf[i] = u.s;
        }
#pragma unroll
        for (int j = 0; j < 4; ++j) {
            const int row = wr * 64 + j * 16 + fr;
            const int g = ks * 4 + fg;
            UFrag u; u.u = ldsA[row * 8 + (g ^ (row & 7))];
            qf[j] = u.s;
        }
#pragma unroll
        for (int i = 0; i < 4; ++i)
#pragma unroll
            for (int j = 0; j < 4; ++j)
                if (!diag || (wr * 64 + j * 16) <= (wc * 64 + i * 16))   // wave-uniform
                    acc[i][j] = __builtin_amdgcn_mfma_f32_16x16x32_bf16(kf[i], qf[j], acc[i][j], 0, 0, 0);
    }
}

// ---------------- K6: recompute einsum, apply (1+scale*sig), mask, tril, /8 ----------------
// Strictly-lower region: (x - 1e12) rounds to exactly -1e12 in fp32 (ULP=65536),
// so those outputs are the bit-exact constant -1e12/8 (or -inf under mask).
// Whole lower 128-tiles AND lower fragments of diagonal tiles take the fill path.
// All out-stores are nontemporal: protect L2-resident sig/qw/kw/ev from eviction.
__global__ __launch_bounds__(256) void k6_final(
    float* __restrict__ ws, float* __restrict__ out, const int* __restrict__ mask)
{
    __shared__ uint4 ldsA[128 * 8];
    __shared__ uint4 ldsB[128 * 8];

    const int tid = threadIdx.x;
    const int mt = blockIdx.x >> 2, nt = blockIdx.x & 3;
    const int c  = blockIdx.y;
    const int b  = blockIdx.z;
    const int m0 = mt * 128, n0 = nt * 128;
    float* outb = out + (size_t)(b * nC + c) * nSS;
    const float CF = -1e12f * 0.125f;

    if (mt > nt) {   // strictly lower: constant fill, coalesced 512B/row per wave
        const int rr0 = tid >> 5;
        const int nn = n0 + (tid & 31) * 4;
        const int4 mc = *(const int4*)(mask + b * nS + nn);
#pragma unroll
        for (int p = 0; p < 16; ++p) {
            const int m = m0 + p * 8 + rr0;
            const int mr = mask[b * nS + m];
            ntstore4(outb + (size_t)m * nS + nn,
                     (mr && mc.x) ? CF : -INFINITY,
                     (mr && mc.y) ? CF : -INFINITY,
                     (mr && mc.z) ? CF : -INFINITY,
                     (mr && mc.w) ? CF : -INFINITY);
        }
        return;
    }
    const bool diag = (mt == nt);

    stage_tiles(ws + QW_OFF + ((size_t)(b * nS + m0)) * nD,
                ws + KW_OFF + ((size_t)(b * nS + n0)) * nD,
                ws + EV_OFF + (size_t)c * nD, ldsA, ldsB, tid);
    __syncthreads();

    const int lane = tid & 63;
    const int wv = tid >> 6;
    const int wr = wv >> 1, wc = wv & 1;
    const int fr = lane & 15, fg = lane >> 4;

    f32x4 acc[4][4] = {};
    mfma_tile(ldsA, ldsB, wr, wc, fr, fg, diag, acc);

    const float scale = ws[SCALE_OFF + b * nC + c];
    const float* sig = ws + SIG_OFF + (size_t)b * nS * nS;

#pragma unroll
    for (int i = 0; i < 4; ++i) {
#pragma unroll
        for (int j = 0; j < 4; ++j) {
            const int m = m0 + wr * 64 + j * 16 + fr;
            const int nb = n0 + wc * 64 + i * 16 + fg * 4;
            const int mrow = mask[b * nS + m];
            const int4 mcol = *(const int4*)(mask + b * nS + nb);
            const int mcv[4] = { mcol.x, mcol.y, mcol.z, mcol.w };
            float r[4];
            if (diag && (wr * 64 + j * 16) > (wc * 64 + i * 16)) {
                // strictly-lower fragment of a diagonal tile: bit-exact constant
#pragma unroll
                for (int rr = 0; rr < 4; ++rr)
                    r[rr] = (mrow && mcv[rr]) ? CF : -INFINITY;
            } else {
                const float4 sg = *(const float4*)(sig + (size_t)m * nS + nb);
                const float sgv[4] = { sg.x, sg.y, sg.z, sg.w };
                const f32x4 a = acc[i][j];
#pragma unroll
                for (int rr = 0; rr < 4; ++rr) {
                    float v = a[rr] * (1.f + scale * sgv[rr]);
                    if (!mrow || !mcv[rr]) v = -INFINITY;
                    if (m > nb + rr) v -= 1e12f;
                    r[rr] = v * 0.125f;
                }
            }
            ntstore4(outb + (size_t)m * nS + nb, r[0], r[1], r[2], r[3]);
        }
    }
}

extern "C" void kernel_launch(void* const* d_in, const int* in_sizes, int n_in,
                              void* d_out, int out_size, void* d_ws, size_t ws_size,
                              hipStream_t stream)
{
    const float* inputs = (const float*)d_in[0];
    const float* evin   = (const float*)d_in[1];
    const int*   mask   = (const int*)d_in[2];
    const float* wd     = (const float*)d_in[3];
    const float* bd     = (const float*)d_in[4];
    const float* we     = (const float*)d_in[5];
    const float* be     = (const float*)d_in[6];
    const float* w1     = (const float*)d_in[7];
    const float* b1     = (const float*)d_in[8];
    const float* w2     = (const float*)d_in[9];
    const float* b2     = (const float*)d_in[10];
    const float* cw     = (const float*)d_in[11];
    float* out = (float*)d_out;
    float* ws  = (float*)d_ws;

    k1_proj<<<256 + nC, 256, 0, stream>>>(inputs, evin, wd, bd, we, be, ws);
    kS_stats<<<dim3(256, nB), 256, 0, stream>>>(ws);
    kC_comp<<<dim3(256, nB), 256, 0, stream>>>(ws, w1, b1, w2, b2);
    k5_conv<<<nB * nS, 512, 0, stream>>>(ws, cw);
    k6_final<<<dim3(16, nC, nB), 256, 0, stream>>>(ws, out, mask);
}